// Round 2
// baseline (514.725 us; speedup 1.0000x reference)
//
#include <hip/hip_runtime.h>
#include <cmath>

// Problem constants
static constexpr int B_  = 16;
static constexpr int N_  = 2048;
static constexpr int NT_ = 32768;     // B_*N_
static constexpr int E_  = 524288;    // NT_*16

// Workspace layout (float-element offsets)
static constexpr size_t OFF_H      = 0;          // NT_*64
static constexpr size_t OFF_XD     = 2097152;    // NT_*128
static constexpr size_t OFF_SWS    = 6291456;    // NT_*32
static constexpr size_t OFF_PART   = 7340032;    // 8*16*32*128
static constexpr size_t OFF_DINV   = 7864320;    // NT_
static constexpr size_t OFF_SHIFT  = 7897088;    // 1024
static constexpr size_t OFF_SCALE  = 7898112;    // 1024
static constexpr size_t OFF_CA     = 7899136;    // 512
static constexpr size_t OFF_CS     = 7899648;    // 512
static constexpr size_t OFF_SS     = 7900160;    // 16384
static constexpr size_t OFF_SPECA  = 7916544;    // 16
static constexpr size_t OFF_MTOT   = 7916560;    // 16
static constexpr size_t OFF_GSUM   = 7916576;    // 1024
static constexpr size_t OFF_GSUM2  = 7917600;    // 1024
// int region (cast float* -> int*)
static constexpr size_t OFF_ICNTI  = 7918624;    // 32768 ints
static constexpr size_t OFF_ICNTO  = 7951392;    // 32768
static constexpr size_t OFF_IROWS  = 7984160;    // 32772
static constexpr size_t OFF_ICURS  = 8016932;    // 32768
static constexpr size_t OFF_IESRC  = 8049700;    // 524288
// total 8573988 floats = 34.3 MiB

__device__ __forceinline__ float selu_f(float x) {
  return 1.0507009873554805f * (x > 0.f ? x : 1.6732632423543772f * expm1f(x));
}

__device__ __forceinline__ float block_sum_bcast(float v, float* sm) {
  int lane = threadIdx.x & 63, w = threadIdx.x >> 6;
#pragma unroll
  for (int off = 32; off; off >>= 1) v += __shfl_down(v, off);
  __syncthreads();
  if (lane == 0) sm[w] = v;
  __syncthreads();
  return sm[0] + sm[1] + sm[2] + sm[3];
}

// ---- init small buffers + int counters ----
__global__ void k_init(int* cin, int* cout_, float* ss, float* gsum,
                       float* gsum2, float* ca, float* cs, float* specA,
                       float* mtot, float* lossp) {  // grid 128 x 256 = 32768
  int i = blockIdx.x * 256 + threadIdx.x;
  cin[i] = 0;
  cout_[i] = 0;
  if (i < 16384) ss[i] = 0.f;
  if (i < 1024) { gsum[i] = 0.f; gsum2[i] = 0.f; }
  if (i < 512)  { ca[i] = 0.f; cs[i] = 0.f; }
  if (i < 16)   { specA[i] = 0.f; mtot[i] = 0.f; }
  if (i == 0)   lossp[0] = 0.f;
}

// ---- degree counting (int) ----
__global__ void k_count(const int* ei, int* cin, int* cout_) {  // grid 2048 x 256
  int e = blockIdx.x * 256 + threadIdx.x;
  atomicAdd(&cout_[ei[e]], 1);        // src (adj row-sum degrees)
  atomicAdd(&cin[ei[E_ + e]], 1);     // dst (GCN in-degree, self-loop added later)
}

// ---- exclusive scan of cin -> rows/cursor, dinv = rsqrt(cin+1) ----
__global__ __launch_bounds__(1024) void k_scan(const int* cin, int* rows,
                                               int* curs, float* dinv) { // grid 1 x 1024
  __shared__ int sm[1024];
  int t = threadIdx.x;
  int4 v[8];
  const int4* p = (const int4*)cin + (size_t)t * 8;
  int loc = 0;
#pragma unroll
  for (int i = 0; i < 8; i++) { v[i] = p[i]; loc += v[i].x + v[i].y + v[i].z + v[i].w; }
  sm[t] = loc;
  __syncthreads();
  for (int off = 1; off < 1024; off <<= 1) {
    int add = (t >= off) ? sm[t - off] : 0;
    __syncthreads();
    sm[t] += add;
    __syncthreads();
  }
  int run = (t > 0) ? sm[t - 1] : 0;
  int base = t * 32;
#pragma unroll
  for (int i = 0; i < 8; i++) {
    int4 c = v[i];
    int j = base + i * 4;
    rows[j] = run; curs[j] = run; dinv[j] = rsqrtf((float)(c.x + 1)); run += c.x;
    rows[j+1] = run; curs[j+1] = run; dinv[j+1] = rsqrtf((float)(c.y + 1)); run += c.y;
    rows[j+2] = run; curs[j+2] = run; dinv[j+2] = rsqrtf((float)(c.z + 1)); run += c.z;
    rows[j+3] = run; curs[j+3] = run; dinv[j+3] = rsqrtf((float)(c.w + 1)); run += c.w;
  }
  if (t == 1023) rows[32768] = run;
}

// ---- bucket edges by dst ----
__global__ void k_bucket(const int* ei, int* curs, int* esrc) {  // grid 2048 x 256
  int e = blockIdx.x * 256 + threadIdx.x;
  int s = ei[e], d = ei[E_ + e];
  int pos = atomicAdd(&curs[d], 1);
  esrc[pos] = s;
}

// ---- GraphNorm stats ----
__global__ void k_gn_part(const float* x, float* gsum, float* gsum2) { // grid 128 x 256
  int b = blockIdx.x >> 3, chunk = blockIdx.x & 7;
  int c = threadIdx.x & 63, r = threadIdx.x >> 6;
  float s = 0.f, s2 = 0.f;
  const float* xb = x + ((size_t)b * N_ + (size_t)chunk * 256) * 64;
  for (int n = r; n < 256; n += 4) {
    float v = xb[n * 64 + c];
    s += v; s2 += v * v;
  }
  __shared__ float l1[4][64], l2[4][64];
  l1[r][c] = s; l2[r][c] = s2;
  __syncthreads();
  if (r == 0) {
    s  = l1[0][c] + l1[1][c] + l1[2][c] + l1[3][c];
    s2 = l2[0][c] + l2[1][c] + l2[2][c] + l2[3][c];
    atomicAdd(&gsum[b * 64 + c], s);
    atomicAdd(&gsum2[b * 64 + c], s2);
  }
}

__global__ void k_gn_fin(const float* gsum, const float* gsum2, const float* gw,
                         const float* gms, float* shift, float* scalev) { // grid 4 x 256
  int i = blockIdx.x * 256 + threadIdx.x;  // < 1024
  int c = i & 63;
  float mean = gsum[i] * (1.f / 2048.f);
  float a = gms[c];
  float var = gsum2[i] * (1.f / 2048.f) - (2.f * a - a * a) * mean * mean;
  shift[i] = a * mean;
  scalev[i] = gw[c] * rsqrtf(var + 1e-5f);
}

// ---- h = graphnorm(x) ----
__global__ void k_h(const float* x, const float* shift, const float* scalev,
                    const float* gb, float* h) {
  int idx = blockIdx.x * 256 + threadIdx.x;  // grid 2048 x 256 = NT_*16
  int node = idx >> 4, g4 = (idx & 15) * 4;
  int b = node >> 11;
  float4 xv = *(const float4*)&x[node * 64 + g4];
  float4 sh = *(const float4*)&shift[b * 64 + g4];
  float4 sc = *(const float4*)&scalev[b * 64 + g4];
  float4 bb = *(const float4*)&gb[g4];
  float4 o;
  o.x = (xv.x - sh.x) * sc.x + bb.x;
  o.y = (xv.y - sh.y) * sc.y + bb.y;
  o.z = (xv.z - sh.z) * sc.z + bb.z;
  o.w = (xv.w - sh.w) * sc.w + bb.w;
  *(float4*)&h[node * 64 + g4] = o;
}

// ---- fused CSR gather + xd = selu(agg @ w1 + b1) ----
__global__ __launch_bounds__(256) void k_mm1(const float* h, const float* dinv,
                                             const int* rows, const int* esrc,
                                             const float* w1, const float* b1,
                                             float* xd) {
  __shared__ float w1s[64 * 128];   // 32 KB
  __shared__ float at[32 * 65];     // padded A-tile
  int tid = threadIdx.x;
  for (int i = tid; i < 8192; i += 256) w1s[i] = w1[i];
  int n0 = blockIdx.x * 32;         // grid 1024
  int wv = tid >> 6, c = tid & 63;
  // gather: each wave owns one node per iteration (uniform edge loop)
  for (int i = 0; i < 8; i++) {
    int nn = i * 4 + wv;
    int node = n0 + nn;
    int e0 = rows[node], e1 = rows[node + 1];
    float dd = dinv[node];
    float acc = dd * h[(size_t)node * 64 + c];   // self-loop (x dd below -> dd^2)
    for (int e = e0; e < e1; e++) {
      int s = esrc[e];
      acc += dinv[s] * h[(size_t)s * 64 + c];
    }
    at[nn * 65 + c] = dd * acc;
  }
  __syncthreads();
  int tx = tid & 31, ty = tid >> 5;
  int f0 = tx * 4, nn = ty * 4;
  float acc[4][4] = {};
  for (int k = 0; k < 64; k++) {
    float4 wvv = *(float4*)&w1s[k * 128 + f0];
#pragma unroll
    for (int i = 0; i < 4; i++) {
      float av = at[(nn + i) * 65 + k];
      acc[i][0] += av * wvv.x; acc[i][1] += av * wvv.y;
      acc[i][2] += av * wvv.z; acc[i][3] += av * wvv.w;
    }
  }
  float4 bv = *(const float4*)&b1[f0];
#pragma unroll
  for (int i = 0; i < 4; i++) {
    float4 o;
    o.x = selu_f(acc[i][0] + bv.x);
    o.y = selu_f(acc[i][1] + bv.y);
    o.z = selu_f(acc[i][2] + bv.z);
    o.w = selu_f(acc[i][3] + bv.w);
    *(float4*)&xd[(size_t)(n0 + nn + i) * 128 + f0] = o;
  }
}

// ---- s = softmax(xd @ w2 + b2); dual-write to ws (aligned) and out (unaligned) ----
__global__ __launch_bounds__(256) void k_mm2s(const float* xd, const float* w2,
                                              const float* b2, float* s_ws,
                                              float* outs) {
  __shared__ float w2s[128 * 32];   // 16 KB
  __shared__ float xt[64 * 129];    // 33 KB
  __shared__ float lg[64 * 33];     // 8.4 KB
  int tid = threadIdx.x;
  for (int i = tid; i < 4096; i += 256) w2s[i] = w2[i];
  int n0 = blockIdx.x * 64;         // grid 512
  for (int i = tid; i < 2048; i += 256) {
    int n = i >> 5, j4 = (i & 31) * 4;
    float4 v = *(const float4*)&xd[(size_t)(n0 + n) * 128 + j4];
    xt[n * 129 + j4] = v.x; xt[n * 129 + j4 + 1] = v.y;
    xt[n * 129 + j4 + 2] = v.z; xt[n * 129 + j4 + 3] = v.w;
  }
  __syncthreads();
  int tx = tid & 7, ty = tid >> 3;
  int k0 = tx * 4;
  float acc[2][4] = {};
  for (int j = 0; j < 128; j++) {
    float4 wv = *(float4*)&w2s[j * 32 + k0];
    float x0 = xt[(ty * 2) * 129 + j];
    float x1 = xt[(ty * 2 + 1) * 129 + j];
    acc[0][0] += x0 * wv.x; acc[0][1] += x0 * wv.y; acc[0][2] += x0 * wv.z; acc[0][3] += x0 * wv.w;
    acc[1][0] += x1 * wv.x; acc[1][1] += x1 * wv.y; acc[1][2] += x1 * wv.z; acc[1][3] += x1 * wv.w;
  }
  float4 bv = *(const float4*)&b2[k0];
#pragma unroll
  for (int i = 0; i < 2; i++) {
    int n = ty * 2 + i;
    lg[n * 33 + k0]     = acc[i][0] + bv.x;
    lg[n * 33 + k0 + 1] = acc[i][1] + bv.y;
    lg[n * 33 + k0 + 2] = acc[i][2] + bv.z;
    lg[n * 33 + k0 + 3] = acc[i][3] + bv.w;
  }
  __syncthreads();
  if (tid < 64) {
    float m = -3.4e38f;
    for (int kk = 0; kk < 32; kk++) m = fmaxf(m, lg[tid * 33 + kk]);
    float ssum = 0.f;
    for (int kk = 0; kk < 32; kk++) {
      float e = expf(lg[tid * 33 + kk] - m);
      lg[tid * 33 + kk] = e; ssum += e;
    }
    float inv = 1.f / ssum;
    for (int k4 = 0; k4 < 32; k4 += 4) {
      float4 o;
      o.x = lg[tid * 33 + k4] * inv;     o.y = lg[tid * 33 + k4 + 1] * inv;
      o.z = lg[tid * 33 + k4 + 2] * inv; o.w = lg[tid * 33 + k4 + 3] * inv;
      *(float4*)&s_ws[(size_t)(n0 + tid) * 32 + k4] = o;
      float* op = &outs[(size_t)(n0 + tid) * 32 + k4];
      op[0] = o.x; op[1] = o.y; op[2] = o.z; op[3] = o.w;
    }
  }
}

// ---- ca[b,k]=sum s*deg_out, csize[b,k]=sum s, mtot[b]=sum deg_out ----
__global__ void k_ca(const float* s_ws, const int* cout_, float* ca,
                     float* cs, float* mtot) {   // grid 128 x 256
  int b = blockIdx.x >> 3, chunk = blockIdx.x & 7;
  int k = threadIdx.x & 31, r = threadIdx.x >> 5;
  float aca = 0.f, acs = 0.f, am = 0.f;
  int nbase = b * 2048 + chunk * 256;
  for (int i = 0; i < 32; i++) {
    int node = nbase + i * 8 + r;
    float dg = (float)cout_[node];
    float v = s_ws[(size_t)node * 32 + k];
    acs += v; aca += v * dg; am += dg;
  }
  __shared__ float r1[8][32], r2[8][32], rm[8];
  r1[r][k] = aca; r2[r][k] = acs;
  if (k == 0) rm[r] = am;
  __syncthreads();
  if (r == 0) {
    float sa = 0.f, sc = 0.f;
#pragma unroll
    for (int i = 0; i < 8; i++) { sa += r1[i][k]; sc += r2[i][k]; }
    atomicAdd(&ca[b * 32 + k], sa);
    atomicAdd(&cs[b * 32 + k], sc);
    if (k == 0) {
      float sm_ = 0.f;
#pragma unroll
      for (int i = 0; i < 8; i++) sm_ += rm[i];
      atomicAdd(&mtot[b], sm_);
    }
  }
}

// ---- trace(S^T A S) per graph via per-edge dot ----
__global__ void k_spec(const int* ei, const float* s_ws, float* specA) { // grid 2048 x 256
  int e = blockIdx.x * 256 + threadIdx.x;
  int s = ei[e], d = ei[E_ + e];
  const float4* a = (const float4*)&s_ws[(size_t)s * 32];
  const float4* c = (const float4*)&s_ws[(size_t)d * 32];
  float acc = 0.f;
#pragma unroll
  for (int i = 0; i < 8; i++) {
    float4 u = a[i], v = c[i];
    acc += u.x * v.x + u.y * v.y + u.z * v.z + u.w * v.w;
  }
#pragma unroll
  for (int off = 32; off; off >>= 1) acc += __shfl_down(acc, off);
  if ((threadIdx.x & 63) == 0) atomicAdd(&specA[blockIdx.x >> 7], acc);
}

// ---- ss[b] = S^T S ----
__global__ __launch_bounds__(256) void k_ss(const float* s_ws, float* ss) { // grid 128
  __shared__ float st[64 * 33];
  int b = blockIdx.x >> 3, chunk = blockIdx.x & 7;
  int tid = threadIdx.x;
  int k = tid >> 3, l0 = (tid & 7) * 4;
  float acc[4] = {};
  for (int sub = 0; sub < 4; sub++) {
    int base = b * 2048 + chunk * 256 + sub * 64;
    __syncthreads();
    for (int i = tid; i < 2048; i += 256) {
      int n = i >> 5, kk = i & 31;
      st[n * 33 + kk] = s_ws[(size_t)(base + n) * 32 + kk];
    }
    __syncthreads();
    for (int n = 0; n < 64; n++) {
      float sk = st[n * 33 + k];
      acc[0] += sk * st[n * 33 + l0];
      acc[1] += sk * st[n * 33 + l0 + 1];
      acc[2] += sk * st[n * 33 + l0 + 2];
      acc[3] += sk * st[n * 33 + l0 + 3];
    }
  }
  atomicAdd(&ss[b * 1024 + k * 32 + l0], acc[0]);
  atomicAdd(&ss[b * 1024 + k * 32 + l0 + 1], acc[1]);
  atomicAdd(&ss[b * 1024 + k * 32 + l0 + 2], acc[2]);
  atomicAdd(&ss[b * 1024 + k * 32 + l0 + 3], acc[3]);
}

// ---- partial out[b,k,f] = sum_n s[n,k]*xd[n,f] over 256-node chunk ----
__global__ __launch_bounds__(256) void k_outp(const float* s_ws, const float* xd,
                                              float* partial) {  // grid 128
  __shared__ float st[64 * 36];
  __shared__ float xt[64 * 132];
  int b = blockIdx.x & 15, chunk = blockIdx.x >> 4;
  int tid = threadIdx.x;
  int tx = tid & 31, ty = tid >> 5;
  int f0 = tx * 4, k0 = ty * 4;
  float acc[4][4] = {};
  for (int sub = 0; sub < 4; sub++) {
    int base = b * 2048 + chunk * 256 + sub * 64;
    __syncthreads();
    for (int i = tid; i < 2048; i += 256) {
      int n = i >> 5, kk = i & 31;
      st[n * 36 + kk] = s_ws[(size_t)(base + n) * 32 + kk];
    }
    for (int i = tid; i < 8192; i += 256) {
      int n = i >> 7, j = i & 127;
      xt[n * 132 + j] = xd[(size_t)(base + n) * 128 + j];
    }
    __syncthreads();
    for (int n = 0; n < 64; n++) {
      float4 sv = *(float4*)&st[n * 36 + k0];
      float4 xv = *(float4*)&xt[n * 132 + f0];
      acc[0][0] += sv.x * xv.x; acc[0][1] += sv.x * xv.y; acc[0][2] += sv.x * xv.z; acc[0][3] += sv.x * xv.w;
      acc[1][0] += sv.y * xv.x; acc[1][1] += sv.y * xv.y; acc[1][2] += sv.y * xv.z; acc[1][3] += sv.y * xv.w;
      acc[2][0] += sv.z * xv.x; acc[2][1] += sv.z * xv.y; acc[2][2] += sv.z * xv.z; acc[2][3] += sv.z * xv.w;
      acc[3][0] += sv.w * xv.x; acc[3][1] += sv.w * xv.y; acc[3][2] += sv.w * xv.z; acc[3][3] += sv.w * xv.w;
    }
  }
  int pbase = (chunk * 16 + b) * 32;
#pragma unroll
  for (int i = 0; i < 4; i++) {
    float4 o = {acc[i][0], acc[i][1], acc[i][2], acc[i][3]};
    *(float4*)&partial[(size_t)(pbase + k0 + i) * 128 + f0] = o;
  }
}

// ---- reduce partials, selu, log_softmax over F=128 ----
__global__ void k_outf(const float* partial, float* out0) {  // grid 512 x 128
  int row = blockIdx.x;
  int b = row >> 5, k = row & 31;
  int f = threadIdx.x;
  float v = 0.f;
#pragma unroll
  for (int c = 0; c < 8; c++) v += partial[(size_t)(((c * 16 + b) * 32 + k)) * 128 + f];
  v = selu_f(v);
  int lane = threadIdx.x & 63, w = threadIdx.x >> 6;
  __shared__ float s1[2], s2[2];
  float m = v;
#pragma unroll
  for (int off = 32; off; off >>= 1) m = fmaxf(m, __shfl_down(m, off));
  if (lane == 0) s1[w] = m;
  __syncthreads();
  m = fmaxf(s1[0], s1[1]);
  float e = expf(v - m), t = e;
#pragma unroll
  for (int off = 32; off; off >>= 1) t += __shfl_down(t, off);
  if (lane == 0) s2[w] = t;
  __syncthreads();
  float tot = s2[0] + s2[1];
  out0[(size_t)row * 128 + f] = v - m - logf(tot);
}

// ---- per-graph losses ----
__global__ void k_loss(const float* ss, const float* cs, const float* ca,
                       const float* specA, const float* mtot, float* loss) { // grid 16 x 256
  int b = blockIdx.x;
  __shared__ float sm[4];
  float ssq = 0.f;
  for (int i = threadIdx.x; i < 1024; i += 256) {
    float v = ss[b * 1024 + i]; ssq += v * v;
  }
  ssq = block_sum_bcast(ssq, sm);
  float inv = 1.f / sqrtf(ssq);
  float dsq = 0.f;
  for (int i = threadIdx.x; i < 1024; i += 256) {
    float v = ss[b * 1024 + i] * inv;
    if ((i >> 5) == (i & 31)) v -= 0.17677669529663687f;  // 1/sqrt(32)
    dsq += v * v;
  }
  dsq = block_sum_bcast(dsq, sm);
  float csq = 0.f, casq = 0.f;
  if (threadIdx.x < 32) {
    float c1 = cs[b * 32 + threadIdx.x]; csq = c1 * c1;
    float c2 = ca[b * 32 + threadIdx.x]; casq = c2 * c2;
  }
  csq = block_sum_bcast(csq, sm);
  casq = block_sum_bcast(casq, sm);
  if (threadIdx.x == 0) {
    float ortho = sqrtf(dsq);
    float cl = sqrtf(csq) * (1.f / 2048.f) * 5.656854249492381f - 1.f;  // *sqrt(32)
    float m = mtot[b] * 0.5f;
    float spec = -(specA[b] - casq / (2.f * m)) / (2.f * m);
    atomicAdd(loss, (spec + ortho + cl) * (1.f / 16.f));
  }
}

extern "C" void kernel_launch(void* const* d_in, const int* in_sizes, int n_in,
                              void* d_out, int out_size, void* d_ws, size_t ws_size,
                              hipStream_t stream) {
  (void)in_sizes; (void)n_in; (void)out_size; (void)ws_size;
  const float* x   = (const float*)d_in[0];
  const int*   ei  = (const int*)d_in[1];
  // d_in[2] = batch (uniform sizes -> unused)
  const float* gw  = (const float*)d_in[3];
  const float* gb  = (const float*)d_in[4];
  const float* gms = (const float*)d_in[5];
  const float* w1  = (const float*)d_in[6];
  const float* b1  = (const float*)d_in[7];
  const float* w2  = (const float*)d_in[8];
  const float* b2  = (const float*)d_in[9];
  float* out = (float*)d_out;
  float* ws  = (float*)d_ws;

  float* h      = ws + OFF_H;
  float* xd     = ws + OFF_XD;
  float* s_ws   = ws + OFF_SWS;
  float* part   = ws + OFF_PART;
  float* dinv   = ws + OFF_DINV;
  float* shift  = ws + OFF_SHIFT;
  float* scalev = ws + OFF_SCALE;
  float* ca     = ws + OFF_CA;
  float* cs     = ws + OFF_CS;
  float* ssb    = ws + OFF_SS;
  float* specA  = ws + OFF_SPECA;
  float* mtot   = ws + OFF_MTOT;
  float* gsum   = ws + OFF_GSUM;
  float* gsum2  = ws + OFF_GSUM2;
  int*   cin    = (int*)(ws + OFF_ICNTI);
  int*   cout_  = (int*)(ws + OFF_ICNTO);
  int*   rows   = (int*)(ws + OFF_IROWS);
  int*   curs   = (int*)(ws + OFF_ICURS);
  int*   esrc   = (int*)(ws + OFF_IESRC);

  float* out0  = out;            // [B,K,HID] log_softmax
  float* lossp = out + 65536;    // scalar
  float* outs  = out + 65537;    // [B,N,K] s

  hipLaunchKernelGGL(k_init, dim3(128), dim3(256), 0, stream,
                     cin, cout_, ssb, gsum, gsum2, ca, cs, specA, mtot, lossp);
  hipLaunchKernelGGL(k_count, dim3(2048), dim3(256), 0, stream, ei, cin, cout_);
  hipLaunchKernelGGL(k_gn_part, dim3(128), dim3(256), 0, stream, x, gsum, gsum2);
  hipLaunchKernelGGL(k_scan, dim3(1), dim3(1024), 0, stream, cin, rows, curs, dinv);
  hipLaunchKernelGGL(k_gn_fin, dim3(4), dim3(256), 0, stream, gsum, gsum2, gw, gms, shift, scalev);
  hipLaunchKernelGGL(k_h, dim3(2048), dim3(256), 0, stream, x, shift, scalev, gb, h);
  hipLaunchKernelGGL(k_bucket, dim3(2048), dim3(256), 0, stream, ei, curs, esrc);
  hipLaunchKernelGGL(k_mm1, dim3(1024), dim3(256), 0, stream, h, dinv, rows, esrc, w1, b1, xd);
  hipLaunchKernelGGL(k_mm2s, dim3(512), dim3(256), 0, stream, xd, w2, b2, s_ws, outs);
  hipLaunchKernelGGL(k_ca, dim3(128), dim3(256), 0, stream, s_ws, cout_, ca, cs, mtot);
  hipLaunchKernelGGL(k_spec, dim3(2048), dim3(256), 0, stream, ei, s_ws, specA);
  hipLaunchKernelGGL(k_ss, dim3(128), dim3(256), 0, stream, s_ws, ssb);
  hipLaunchKernelGGL(k_outp, dim3(128), dim3(256), 0, stream, s_ws, xd, part);
  hipLaunchKernelGGL(k_outf, dim3(512), dim3(128), 0, stream, part, out0);
  hipLaunchKernelGGL(k_loss, dim3(16), dim3(256), 0, stream, ssb, cs, ca, specA, mtot, lossp);
}

// Round 3
// 312.956 us; speedup vs baseline: 1.6447x; 1.6447x over previous
//
#include <hip/hip_runtime.h>
#include <cmath>

static constexpr int B_  = 16;
static constexpr int N_  = 2048;
static constexpr int NT_ = 32768;
static constexpr int E_  = 524288;

// Workspace layout (float-element offsets)
static constexpr size_t OFF_HSC    = 0;          // NT_*64  (dinv-scaled graphnorm rows)
static constexpr size_t OFF_XD     = 2097152;    // NT_*128
static constexpr size_t OFF_SWS    = 6291456;    // NT_*32
static constexpr size_t OFF_PART   = 7340032;    // 16*16*32*128
static constexpr size_t OFF_DINV   = 8388608;    // NT_
static constexpr size_t OFF_SHIFT  = 8421376;    // 1024
static constexpr size_t OFF_SCALE  = 8422400;    // 1024
static constexpr size_t OFF_GSP    = 8423424;    // 128*64
static constexpr size_t OFF_GSP2   = 8431616;    // 128*64
static constexpr size_t OFF_SSP    = 8439808;    // 256*1024
static constexpr size_t OFF_CAP    = 8701952;    // 256*32
static constexpr size_t OFF_CSP    = 8710144;    // 256*32
static constexpr size_t OFF_SPECP  = 8718336;    // 256
static constexpr size_t OFF_ICNTI  = 8718592;    // 32768 ints
static constexpr size_t OFF_ICNTO  = 8751360;    // 32768
static constexpr size_t OFF_IROWS  = 8784128;    // 32772
static constexpr size_t OFF_ICURS  = 8816900;    // 32768
static constexpr size_t OFF_IESRC  = 8849668;    // 524288
// total 9373956 floats = 35.8 MiB

__device__ __forceinline__ float selu_f(float x) {
  return 1.0507009873554805f * (x > 0.f ? x : 1.6732632423543772f * expm1f(x));
}

__device__ __forceinline__ float block_sum_bcast(float v, float* sm) {
  int lane = threadIdx.x & 63, w = threadIdx.x >> 6;
#pragma unroll
  for (int off = 32; off; off >>= 1) v += __shfl_down(v, off);
  __syncthreads();
  if (lane == 0) sm[w] = v;
  __syncthreads();
  return sm[0] + sm[1] + sm[2] + sm[3];
}

// ---- zero counters + loss ----
__global__ void k_init(int* cin, int* cout_, float* lossp) {  // grid 128 x 256
  int i = blockIdx.x * 256 + threadIdx.x;
  cin[i] = 0;
  cout_[i] = 0;
  if (i == 0) lossp[0] = 0.f;
}

// ---- fused: degree counting (blocks <2048) + GraphNorm partial stats ----
__global__ void k_count_gn(const int* ei, const float* x, int* cin, int* cout_,
                           float* gsp, float* gsp2) {  // grid 2176 x 256
  __shared__ float l1[4][64], l2[4][64];
  int blk = blockIdx.x;
  if (blk < 2048) {
    int e = blk * 256 + threadIdx.x;
    atomicAdd(&cout_[ei[e]], 1);        // src out-degree (adj row-sums)
    atomicAdd(&cin[ei[E_ + e]], 1);     // dst in-degree (GCN, +1 self-loop later)
  } else {
    int gi = blk - 2048;                // 0..127: b = gi>>3, chunk = gi&7
    int b = gi >> 3, chunk = gi & 7;
    int c = threadIdx.x & 63, r = threadIdx.x >> 6;
    float s = 0.f, s2 = 0.f;
    const float* xb = x + ((size_t)b * N_ + (size_t)chunk * 256) * 64;
    for (int n = r; n < 256; n += 4) {
      float v = xb[n * 64 + c];
      s += v; s2 += v * v;
    }
    l1[r][c] = s; l2[r][c] = s2;
    __syncthreads();
    if (r == 0) {
      gsp[gi * 64 + c]  = l1[0][c] + l1[1][c] + l1[2][c] + l1[3][c];
      gsp2[gi * 64 + c] = l2[0][c] + l2[1][c] + l2[2][c] + l2[3][c];
    }
  }
}

// ---- block0: exclusive scan of cin -> rows/curs, dinv; block1: gn finalize ----
__global__ __launch_bounds__(1024) void k_scan_fin(const int* cin, int* rows, int* curs,
    float* dinv, const float* gsp, const float* gsp2, const float* gw, const float* gms,
    float* shift, float* scalev) {  // grid 2 x 1024
  __shared__ int sm[1024];
  int t = threadIdx.x;
  if (blockIdx.x == 1) {
    int b = t >> 6, c = t & 63;
    float s = 0.f, s2 = 0.f;
#pragma unroll
    for (int chunk = 0; chunk < 8; chunk++) {
      s  += gsp[(b * 8 + chunk) * 64 + c];
      s2 += gsp2[(b * 8 + chunk) * 64 + c];
    }
    float mean = s * (1.f / 2048.f);
    float a = gms[c];
    float var = s2 * (1.f / 2048.f) - (2.f * a - a * a) * mean * mean;
    shift[t] = a * mean;
    scalev[t] = gw[c] * rsqrtf(var + 1e-5f);
    return;
  }
  int4 v[8];
  const int4* p = (const int4*)cin + (size_t)t * 8;
  int loc = 0;
#pragma unroll
  for (int i = 0; i < 8; i++) { v[i] = p[i]; loc += v[i].x + v[i].y + v[i].z + v[i].w; }
  sm[t] = loc;
  __syncthreads();
  for (int off = 1; off < 1024; off <<= 1) {
    int add = (t >= off) ? sm[t - off] : 0;
    __syncthreads();
    sm[t] += add;
    __syncthreads();
  }
  int run = (t > 0) ? sm[t - 1] : 0;
  int base = t * 32;
#pragma unroll
  for (int i = 0; i < 8; i++) {
    int4 c = v[i];
    int j = base + i * 4;
    rows[j] = run; curs[j] = run; dinv[j] = rsqrtf((float)(c.x + 1)); run += c.x;
    rows[j+1] = run; curs[j+1] = run; dinv[j+1] = rsqrtf((float)(c.y + 1)); run += c.y;
    rows[j+2] = run; curs[j+2] = run; dinv[j+2] = rsqrtf((float)(c.z + 1)); run += c.z;
    rows[j+3] = run; curs[j+3] = run; dinv[j+3] = rsqrtf((float)(c.w + 1)); run += c.w;
  }
  if (t == 1023) rows[32768] = run;
}

// ---- fused: hsc = dinv * graphnorm(x)  +  CSR bucket ----
__global__ void k_prep(const float* x, const float* shift, const float* scalev,
                       const float* gb, const float* dinv, float* hsc,
                       const int* ei, int* curs, int* esrc) {  // grid 2048 x 256
  int idx = blockIdx.x * 256 + threadIdx.x;   // 0..E_-1
  int node = idx >> 4, g4 = (idx & 15) * 4;
  int b = node >> 11;
  float di = dinv[node];
  float4 xv = *(const float4*)&x[(size_t)node * 64 + g4];
  float4 sh = *(const float4*)&shift[b * 64 + g4];
  float4 sc = *(const float4*)&scalev[b * 64 + g4];
  float4 bb = *(const float4*)&gb[g4];
  float4 o;
  o.x = ((xv.x - sh.x) * sc.x + bb.x) * di;
  o.y = ((xv.y - sh.y) * sc.y + bb.y) * di;
  o.z = ((xv.z - sh.z) * sc.z + bb.z) * di;
  o.w = ((xv.w - sh.w) * sc.w + bb.w) * di;
  *(float4*)&hsc[(size_t)node * 64 + g4] = o;
  // bucket one edge
  int s = ei[idx], d = ei[E_ + idx];
  int pos = atomicAdd(&curs[d], 1);
  esrc[pos] = s;
}

// ---- fused CSR gather (8-deep MLP) + xd = selu(agg @ w1 + b1) ----
__global__ __launch_bounds__(256) void k_mm1(const float* hsc, const float* dinv,
                                             const int* rows, const int* esrc,
                                             const float* w1, const float* b1,
                                             float* xd) {  // grid 1024
  __shared__ float w1s[64 * 128];   // 32 KB
  __shared__ float at[32 * 65];
  int tid = threadIdx.x;
  for (int i = tid; i < 8192; i += 256) w1s[i] = w1[i];
  int n0 = blockIdx.x * 32;
  int wv = tid >> 6, c = tid & 63;
  for (int i = 0; i < 8; i++) {
    int nn = i * 4 + wv;
    int node = n0 + nn;
    int e0 = rows[node], e1 = rows[node + 1];
    float dd = dinv[node];
    float acc = hsc[(size_t)node * 64 + c];    // self-loop term
    for (int e = e0; e < e1; e += 8) {
      int sidx[8]; float wt[8], hv[8];
#pragma unroll
      for (int j = 0; j < 8; j++) {
        int ee = e + j;
        sidx[j] = esrc[ee < e1 ? ee : e0];
        wt[j] = (ee < e1) ? 1.f : 0.f;
      }
#pragma unroll
      for (int j = 0; j < 8; j++) hv[j] = hsc[(size_t)sidx[j] * 64 + c];
#pragma unroll
      for (int j = 0; j < 8; j++) acc += wt[j] * hv[j];
    }
    at[nn * 65 + c] = dd * acc;
  }
  __syncthreads();
  int tx = tid & 31, ty = tid >> 5;
  int f0 = tx * 4, nn = ty * 4;
  float acc[4][4] = {};
  for (int k = 0; k < 64; k++) {
    float4 wvv = *(float4*)&w1s[k * 128 + f0];
#pragma unroll
    for (int i = 0; i < 4; i++) {
      float av = at[(nn + i) * 65 + k];
      acc[i][0] += av * wvv.x; acc[i][1] += av * wvv.y;
      acc[i][2] += av * wvv.z; acc[i][3] += av * wvv.w;
    }
  }
  float4 bv = *(const float4*)&b1[f0];
#pragma unroll
  for (int i = 0; i < 4; i++) {
    float4 o;
    o.x = selu_f(acc[i][0] + bv.x);
    o.y = selu_f(acc[i][1] + bv.y);
    o.z = selu_f(acc[i][2] + bv.z);
    o.w = selu_f(acc[i][3] + bv.w);
    *(float4*)&xd[(size_t)(n0 + nn + i) * 128 + f0] = o;
  }
}

// ---- s = softmax(xd @ w2 + b2); dual-write ws + out ----
__global__ __launch_bounds__(256) void k_mm2s(const float* xd, const float* w2,
                                              const float* b2, float* s_ws,
                                              float* outs) {  // grid 512
  __shared__ float w2s[128 * 32];
  __shared__ float xt[64 * 129];
  __shared__ float lg[64 * 33];
  int tid = threadIdx.x;
  for (int i = tid; i < 4096; i += 256) w2s[i] = w2[i];
  int n0 = blockIdx.x * 64;
  for (int i = tid; i < 2048; i += 256) {
    int n = i >> 5, j4 = (i & 31) * 4;
    float4 v = *(const float4*)&xd[(size_t)(n0 + n) * 128 + j4];
    xt[n * 129 + j4] = v.x; xt[n * 129 + j4 + 1] = v.y;
    xt[n * 129 + j4 + 2] = v.z; xt[n * 129 + j4 + 3] = v.w;
  }
  __syncthreads();
  int ty = tid >> 3;
  int k0 = (tid & 7) * 4;
  float acc[2][4] = {};
  for (int j = 0; j < 128; j++) {
    float4 wv = *(float4*)&w2s[j * 32 + k0];
    float x0 = xt[(ty * 2) * 129 + j];
    float x1 = xt[(ty * 2 + 1) * 129 + j];
    acc[0][0] += x0 * wv.x; acc[0][1] += x0 * wv.y; acc[0][2] += x0 * wv.z; acc[0][3] += x0 * wv.w;
    acc[1][0] += x1 * wv.x; acc[1][1] += x1 * wv.y; acc[1][2] += x1 * wv.z; acc[1][3] += x1 * wv.w;
  }
  float4 bv = *(const float4*)&b2[k0];
#pragma unroll
  for (int i = 0; i < 2; i++) {
    int n = ty * 2 + i;
    lg[n * 33 + k0]     = acc[i][0] + bv.x;
    lg[n * 33 + k0 + 1] = acc[i][1] + bv.y;
    lg[n * 33 + k0 + 2] = acc[i][2] + bv.z;
    lg[n * 33 + k0 + 3] = acc[i][3] + bv.w;
  }
  __syncthreads();
  if (tid < 64) {
    float m = -3.4e38f;
    for (int kk = 0; kk < 32; kk++) m = fmaxf(m, lg[tid * 33 + kk]);
    float ssum = 0.f;
    for (int kk = 0; kk < 32; kk++) {
      float e = expf(lg[tid * 33 + kk] - m);
      lg[tid * 33 + kk] = e; ssum += e;
    }
    float inv = 1.f / ssum;
    for (int k4 = 0; k4 < 32; k4 += 4) {
      float4 o;
      o.x = lg[tid * 33 + k4] * inv;     o.y = lg[tid * 33 + k4 + 1] * inv;
      o.z = lg[tid * 33 + k4 + 2] * inv; o.w = lg[tid * 33 + k4 + 3] * inv;
      *(float4*)&s_ws[(size_t)(n0 + tid) * 32 + k4] = o;
      float* op = &outs[(size_t)(n0 + tid) * 32 + k4];
      op[0] = o.x; op[1] = o.y; op[2] = o.z; op[3] = o.w;
    }
  }
}

// ---- fused per-chunk stats: S^T S partial, ca/cs partial, spec partial ----
__global__ __launch_bounds__(256) void k_stats(const float* s_ws, const int* cout_,
    const int* ei, float* ssp, float* cap, float* csp, float* specp) { // grid 256
  __shared__ float st[128 * 33];
  __shared__ float r1[8][32], r2[8][32];
  __shared__ float sm4[4];
  int blk = blockIdx.x;
  int b = blk >> 4, chunk = blk & 15;
  int tid = threadIdx.x;
  int nbase = b * 2048 + chunk * 128;
  for (int i = tid; i < 4096; i += 256) {
    int n = i >> 5, kk = i & 31;
    st[n * 33 + kk] = s_ws[(size_t)(nbase + n) * 32 + kk];
  }
  __syncthreads();
  // S^T S partial
  int k = tid >> 3, l0 = (tid & 7) * 4;
  float a0 = 0, a1 = 0, a2 = 0, a3 = 0;
  for (int n = 0; n < 128; n++) {
    float sk = st[n * 33 + k];
    a0 += sk * st[n * 33 + l0];     a1 += sk * st[n * 33 + l0 + 1];
    a2 += sk * st[n * 33 + l0 + 2]; a3 += sk * st[n * 33 + l0 + 3];
  }
  float4 o = {a0, a1, a2, a3};
  *(float4*)&ssp[(size_t)blk * 1024 + k * 32 + l0] = o;
  // ca / cs partial
  int k2 = tid & 31, r = tid >> 5;
  float aca = 0.f, acs = 0.f;
  for (int i = 0; i < 16; i++) {
    int n = i * 8 + r;
    float dg = (float)cout_[nbase + n];
    float v = st[n * 33 + k2];
    acs += v; aca += v * dg;
  }
  r1[r][k2] = aca; r2[r][k2] = acs;
  __syncthreads();
  if (r == 0) {
    float sa = 0.f, sc = 0.f;
#pragma unroll
    for (int i = 0; i < 8; i++) { sa += r1[i][k2]; sc += r2[i][k2]; }
    cap[blk * 32 + k2] = sa;
    csp[blk * 32 + k2] = sc;
  }
  // spec partial: this graph's edge slice (edges are grouped by graph)
  int ebase = b * 32768 + chunk * 2048;
  float acc = 0.f;
  for (int j = 0; j < 8; j++) {
    int e = ebase + j * 256 + tid;
    int s = ei[e], d = ei[E_ + e];
    const float4* ap = (const float4*)&s_ws[(size_t)s * 32];
    const float4* cp = (const float4*)&s_ws[(size_t)d * 32];
#pragma unroll
    for (int q = 0; q < 8; q++) {
      float4 u = ap[q], v = cp[q];
      acc += u.x * v.x + u.y * v.y + u.z * v.z + u.w * v.w;
    }
  }
  int lane = tid & 63, w = tid >> 6;
#pragma unroll
  for (int off = 32; off; off >>= 1) acc += __shfl_down(acc, off);
  __syncthreads();
  if (lane == 0) sm4[w] = acc;
  __syncthreads();
  if (tid == 0) specp[blk] = sm4[0] + sm4[1] + sm4[2] + sm4[3];
}

// ---- partial out[b,k,f] over 128-node chunks ----
__global__ __launch_bounds__(256) void k_outp(const float* s_ws, const float* xd,
                                              float* partial) {  // grid 256
  __shared__ float st[64 * 36];
  __shared__ float xt[64 * 132];
  int b = blockIdx.x & 15, chunk = blockIdx.x >> 4;
  int tid = threadIdx.x;
  int tx = tid & 31, ty = tid >> 5;
  int f0 = tx * 4, k0 = ty * 4;
  float acc[4][4] = {};
  for (int sub = 0; sub < 2; sub++) {
    int base = b * 2048 + chunk * 128 + sub * 64;
    __syncthreads();
    for (int i = tid; i < 2048; i += 256) {
      int n = i >> 5, kk = i & 31;
      st[n * 36 + kk] = s_ws[(size_t)(base + n) * 32 + kk];
    }
    for (int i = tid; i < 8192; i += 256) {
      int n = i >> 7, j = i & 127;
      xt[n * 132 + j] = xd[(size_t)(base + n) * 128 + j];
    }
    __syncthreads();
    for (int n = 0; n < 64; n++) {
      float4 sv = *(float4*)&st[n * 36 + k0];
      float4 xv = *(float4*)&xt[n * 132 + f0];
      acc[0][0] += sv.x * xv.x; acc[0][1] += sv.x * xv.y; acc[0][2] += sv.x * xv.z; acc[0][3] += sv.x * xv.w;
      acc[1][0] += sv.y * xv.x; acc[1][1] += sv.y * xv.y; acc[1][2] += sv.y * xv.z; acc[1][3] += sv.y * xv.w;
      acc[2][0] += sv.z * xv.x; acc[2][1] += sv.z * xv.y; acc[2][2] += sv.z * xv.z; acc[2][3] += sv.z * xv.w;
      acc[3][0] += sv.w * xv.x; acc[3][1] += sv.w * xv.y; acc[3][2] += sv.w * xv.z; acc[3][3] += sv.w * xv.w;
    }
  }
  int pbase = (chunk * 16 + b) * 32;
#pragma unroll
  for (int i = 0; i < 4; i++) {
    float4 o = {acc[i][0], acc[i][1], acc[i][2], acc[i][3]};
    *(float4*)&partial[(size_t)(pbase + k0 + i) * 128 + f0] = o;
  }
}

// ---- reduce 16 partials, selu, log_softmax over F=128 ----
__global__ void k_outf(const float* partial, float* out0) {  // grid 512 x 128
  int row = blockIdx.x;
  int b = row >> 5, k = row & 31;
  int f = threadIdx.x;
  float v = 0.f;
#pragma unroll
  for (int c = 0; c < 16; c++) v += partial[(size_t)(((c * 16 + b) * 32 + k)) * 128 + f];
  v = selu_f(v);
  int lane = threadIdx.x & 63, w = threadIdx.x >> 6;
  __shared__ float s1[2], s2[2];
  float m = v;
#pragma unroll
  for (int off = 32; off; off >>= 1) m = fmaxf(m, __shfl_down(m, off));
  if (lane == 0) s1[w] = m;
  __syncthreads();
  m = fmaxf(s1[0], s1[1]);
  float e = expf(v - m), t = e;
#pragma unroll
  for (int off = 32; off; off >>= 1) t += __shfl_down(t, off);
  if (lane == 0) s2[w] = t;
  __syncthreads();
  float tot = s2[0] + s2[1];
  out0[(size_t)row * 128 + f] = v - m - logf(tot);
}

// ---- per-graph losses from partials ----
__global__ void k_loss(const float* ssp, const float* csp, const float* cap,
                       const float* specp, float* loss) { // grid 16 x 256
  int b = blockIdx.x;
  __shared__ float sm[4];
  int tid = threadIdx.x;
  float v0 = 0, v1 = 0, v2 = 0, v3 = 0;
  for (int c = 0; c < 16; c++) {
    float4 u = *(const float4*)&ssp[(size_t)(b * 16 + c) * 1024 + tid * 4];
    v0 += u.x; v1 += u.y; v2 += u.z; v3 += u.w;
  }
  float ssq = v0 * v0 + v1 * v1 + v2 * v2 + v3 * v3;
  ssq = block_sum_bcast(ssq, sm);
  float inv = 1.f / sqrtf(ssq);
  float dsq = 0.f;
  {
    int i0 = tid * 4;
    float vv[4] = {v0, v1, v2, v3};
#pragma unroll
    for (int j = 0; j < 4; j++) {
      int i = i0 + j;
      float d = vv[j] * inv;
      if ((i >> 5) == (i & 31)) d -= 0.17677669529663687f;  // 1/sqrt(32)
      dsq += d * d;
    }
  }
  dsq = block_sum_bcast(dsq, sm);
  float csq = 0.f, casq = 0.f;
  if (tid < 32) {
    float c1 = 0.f, c2 = 0.f;
    for (int c = 0; c < 16; c++) {
      c1 += csp[(size_t)(b * 16 + c) * 32 + tid];
      c2 += cap[(size_t)(b * 16 + c) * 32 + tid];
    }
    csq = c1 * c1; casq = c2 * c2;
  }
  csq = block_sum_bcast(csq, sm);
  casq = block_sum_bcast(casq, sm);
  float spec_sum = (tid < 16) ? specp[b * 16 + tid] : 0.f;
  spec_sum = block_sum_bcast(spec_sum, sm);
  if (tid == 0) {
    float ortho = sqrtf(dsq);
    float cl = sqrtf(csq) * (1.f / 2048.f) * 5.656854249492381f - 1.f;
    float m = 16384.f;  // exactly 32768 edges per graph / 2
    float spec = -(spec_sum - casq / (2.f * m)) / (2.f * m);
    atomicAdd(loss, (spec + ortho + cl) * (1.f / 16.f));
  }
}

extern "C" void kernel_launch(void* const* d_in, const int* in_sizes, int n_in,
                              void* d_out, int out_size, void* d_ws, size_t ws_size,
                              hipStream_t stream) {
  (void)in_sizes; (void)n_in; (void)out_size; (void)ws_size;
  const float* x   = (const float*)d_in[0];
  const int*   ei  = (const int*)d_in[1];
  const float* gw  = (const float*)d_in[3];
  const float* gb  = (const float*)d_in[4];
  const float* gms = (const float*)d_in[5];
  const float* w1  = (const float*)d_in[6];
  const float* b1  = (const float*)d_in[7];
  const float* w2  = (const float*)d_in[8];
  const float* b2  = (const float*)d_in[9];
  float* out = (float*)d_out;
  float* ws  = (float*)d_ws;

  float* hsc    = ws + OFF_HSC;
  float* xd     = ws + OFF_XD;
  float* s_ws   = ws + OFF_SWS;
  float* part   = ws + OFF_PART;
  float* dinv   = ws + OFF_DINV;
  float* shift  = ws + OFF_SHIFT;
  float* scalev = ws + OFF_SCALE;
  float* gsp    = ws + OFF_GSP;
  float* gsp2   = ws + OFF_GSP2;
  float* ssp    = ws + OFF_SSP;
  float* cap    = ws + OFF_CAP;
  float* csp    = ws + OFF_CSP;
  float* specp  = ws + OFF_SPECP;
  int*   cin    = (int*)(ws + OFF_ICNTI);
  int*   cout_  = (int*)(ws + OFF_ICNTO);
  int*   rows   = (int*)(ws + OFF_IROWS);
  int*   curs   = (int*)(ws + OFF_ICURS);
  int*   esrc   = (int*)(ws + OFF_IESRC);

  float* out0  = out;            // [B,K,HID]
  float* lossp = out + 65536;    // scalar
  float* outs  = out + 65537;    // [B,N,K]

  hipLaunchKernelGGL(k_init, dim3(128), dim3(256), 0, stream, cin, cout_, lossp);
  hipLaunchKernelGGL(k_count_gn, dim3(2176), dim3(256), 0, stream, ei, x, cin, cout_, gsp, gsp2);
  hipLaunchKernelGGL(k_scan_fin, dim3(2), dim3(1024), 0, stream,
                     cin, rows, curs, dinv, gsp, gsp2, gw, gms, shift, scalev);
  hipLaunchKernelGGL(k_prep, dim3(2048), dim3(256), 0, stream,
                     x, shift, scalev, gb, dinv, hsc, ei, curs, esrc);
  hipLaunchKernelGGL(k_mm1, dim3(1024), dim3(256), 0, stream, hsc, dinv, rows, esrc, w1, b1, xd);
  hipLaunchKernelGGL(k_mm2s, dim3(512), dim3(256), 0, stream, xd, w2, b2, s_ws, outs);
  hipLaunchKernelGGL(k_stats, dim3(256), dim3(256), 0, stream, s_ws, cout_, ei, ssp, cap, csp, specp);
  hipLaunchKernelGGL(k_outp, dim3(256), dim3(256), 0, stream, s_ws, xd, part);
  hipLaunchKernelGGL(k_outf, dim3(512), dim3(128), 0, stream, part, out0);
  hipLaunchKernelGGL(k_loss, dim3(16), dim3(256), 0, stream, ssp, csp, cap, specp, lossp);
}

// Round 4
// 230.460 us; speedup vs baseline: 2.2335x; 1.3580x over previous
//
#include <hip/hip_runtime.h>
#include <cmath>

static constexpr int B_  = 16;
static constexpr int N_  = 2048;
static constexpr int NT_ = 32768;
static constexpr int E_  = 524288;

// Workspace layout (float-element offsets)
static constexpr size_t OFF_HSC    = 0;          // NT_*64  (dinv-scaled graphnorm rows)
static constexpr size_t OFF_XD     = 2097152;    // NT_*128
static constexpr size_t OFF_SWS    = 6291456;    // NT_*32
static constexpr size_t OFF_PART   = 7340032;    // 16*16*32*128
static constexpr size_t OFF_DINV   = 8388608;    // NT_
static constexpr size_t OFF_SHIFT  = 8421376;    // 1024
static constexpr size_t OFF_SCALE  = 8422400;    // 1024
static constexpr size_t OFF_GSP    = 8423424;    // 128*64
static constexpr size_t OFF_GSP2   = 8431616;    // 128*64
static constexpr size_t OFF_SSP    = 8439808;    // 256*1024
static constexpr size_t OFF_CAP    = 8701952;    // 256*32
static constexpr size_t OFF_CSP    = 8710144;    // 256*32
static constexpr size_t OFF_SPECP  = 8718336;    // 256
static constexpr size_t OFF_ICNTO  = 8718592;    // 32768 ints (out-degrees)
static constexpr size_t OFF_IROWS  = 8751360;    // 32772
static constexpr size_t OFF_IESRC  = 8784132;    // 524288
// total 9308420 floats = 35.5 MiB

__device__ __forceinline__ float selu_f(float x) {
  return 1.0507009873554805f * (x > 0.f ? x : 1.6732632423543772f * expm1f(x));
}

__device__ __forceinline__ float block_sum_bcast(float v, float* sm) {
  int lane = threadIdx.x & 63, w = threadIdx.x >> 6;
#pragma unroll
  for (int off = 32; off; off >>= 1) v += __shfl_down(v, off);
  __syncthreads();
  if (lane == 0) sm[w] = v;
  __syncthreads();
  return sm[0] + sm[1] + sm[2] + sm[3];
}

// ---- fused: per-graph CSR build (count+scan+bucket, all LDS) + GraphNorm partials ----
// blocks 0..15: graph blocks (one graph each); blocks 16..143: gn stat blocks
__global__ __launch_bounds__(1024) void k_graph(const int* ei, const float* x,
                                                int* rows, int* esrc, int* cout_,
                                                float* dinv, float* gsp, float* gsp2) {
  __shared__ int hin[2048], hout[2048], sb[1024];   // 20 KB
  __shared__ float l1[16][64], l2[16][64];          // 8 KB
  int blk = blockIdx.x;
  int tid = threadIdx.x;
  if (blk < 16) {
    int g = blk;
    int nbase = g * 2048;
    int ebase = g * 32768;
    // zero hists
    hin[tid] = 0; hin[tid + 1024] = 0;
    hout[tid] = 0; hout[tid + 1024] = 0;
    __syncthreads();
    // count (LDS atomics)
    for (int i = tid; i < 32768; i += 1024) {
      int s = ei[ebase + i];
      int d = ei[E_ + ebase + i];
      atomicAdd(&hout[s - nbase], 1);
      atomicAdd(&hin[d - nbase], 1);
    }
    __syncthreads();
    // exclusive scan of hin over 2048 (2 elems/thread)
    int a = hin[2 * tid], b2 = hin[2 * tid + 1];
    sb[tid] = a + b2;
    __syncthreads();
    for (int off = 1; off < 1024; off <<= 1) {
      int add = (tid >= off) ? sb[tid - off] : 0;
      __syncthreads();
      sb[tid] += add;
      __syncthreads();
    }
    int pref = (tid > 0) ? sb[tid - 1] : 0;
    int r0 = ebase + pref, r1 = r0 + a;
    int n0 = nbase + 2 * tid;
    rows[n0] = r0; rows[n0 + 1] = r1;
    dinv[n0] = rsqrtf((float)(a + 1));
    dinv[n0 + 1] = rsqrtf((float)(b2 + 1));
    cout_[n0] = hout[2 * tid];
    cout_[n0 + 1] = hout[2 * tid + 1];
    if (blk == 15 && tid == 1023) rows[NT_] = E_;
    __syncthreads();
    // cursors (absolute) back into hin
    hin[2 * tid] = r0; hin[2 * tid + 1] = r1;
    __syncthreads();
    // bucket
    for (int i = tid; i < 32768; i += 1024) {
      int s = ei[ebase + i];
      int d = ei[E_ + ebase + i];
      int pos = atomicAdd(&hin[d - nbase], 1);
      esrc[pos] = s;
    }
  } else {
    int gi = blk - 16;                // 0..127
    int b = gi >> 3, chunk = gi & 7;
    int c = tid & 63, r = tid >> 6;   // r: 0..15
    float s = 0.f, s2 = 0.f;
    const float* xb = x + ((size_t)b * N_ + (size_t)chunk * 256) * 64;
    for (int n = r; n < 256; n += 16) {
      float v = xb[n * 64 + c];
      s += v; s2 += v * v;
    }
    l1[r][c] = s; l2[r][c] = s2;
    __syncthreads();
    if (r == 0) {
      float t1 = 0.f, t2 = 0.f;
#pragma unroll
      for (int i = 0; i < 16; i++) { t1 += l1[i][c]; t2 += l2[i][c]; }
      gsp[gi * 64 + c] = t1;
      gsp2[gi * 64 + c] = t2;
    }
  }
}

// ---- gn finalize (+ zero loss) ----
__global__ __launch_bounds__(1024) void k_fin(const float* gsp, const float* gsp2,
                                              const float* gw, const float* gms,
                                              float* shift, float* scalev, float* lossp) {
  int t = threadIdx.x;   // grid 1 x 1024
  int b = t >> 6, c = t & 63;
  float s = 0.f, s2 = 0.f;
#pragma unroll
  for (int chunk = 0; chunk < 8; chunk++) {
    s  += gsp[(b * 8 + chunk) * 64 + c];
    s2 += gsp2[(b * 8 + chunk) * 64 + c];
  }
  float mean = s * (1.f / 2048.f);
  float a = gms[c];
  float var = s2 * (1.f / 2048.f) - (2.f * a - a * a) * mean * mean;
  shift[t] = a * mean;
  scalev[t] = gw[c] * rsqrtf(var + 1e-5f);
  if (t == 0) lossp[0] = 0.f;
}

// ---- hsc = dinv * graphnorm(x) ----
__global__ void k_prep(const float* x, const float* shift, const float* scalev,
                       const float* gb, const float* dinv, float* hsc) { // grid 2048 x 256
  int idx = blockIdx.x * 256 + threadIdx.x;
  int node = idx >> 4, g4 = (idx & 15) * 4;
  int b = node >> 11;
  float di = dinv[node];
  float4 xv = *(const float4*)&x[(size_t)node * 64 + g4];
  float4 sh = *(const float4*)&shift[b * 64 + g4];
  float4 sc = *(const float4*)&scalev[b * 64 + g4];
  float4 bb = *(const float4*)&gb[g4];
  float4 o;
  o.x = ((xv.x - sh.x) * sc.x + bb.x) * di;
  o.y = ((xv.y - sh.y) * sc.y + bb.y) * di;
  o.z = ((xv.z - sh.z) * sc.z + bb.z) * di;
  o.w = ((xv.w - sh.w) * sc.w + bb.w) * di;
  *(float4*)&hsc[(size_t)node * 64 + g4] = o;
}

// ---- fused CSR gather (8-deep MLP) + xd = selu(agg @ w1 + b1) ----
__global__ __launch_bounds__(256) void k_mm1(const float* hsc, const float* dinv,
                                             const int* rows, const int* esrc,
                                             const float* w1, const float* b1,
                                             float* xd) {  // grid 1024
  __shared__ float w1s[64 * 128];
  __shared__ float at[32 * 65];
  int tid = threadIdx.x;
  for (int i = tid; i < 8192; i += 256) w1s[i] = w1[i];
  int n0 = blockIdx.x * 32;
  int wv = tid >> 6, c = tid & 63;
  for (int i = 0; i < 8; i++) {
    int nn = i * 4 + wv;
    int node = n0 + nn;
    int e0 = rows[node], e1 = rows[node + 1];
    float dd = dinv[node];
    float acc = hsc[(size_t)node * 64 + c];
    for (int e = e0; e < e1; e += 8) {
      int sidx[8]; float wt[8], hv[8];
#pragma unroll
      for (int j = 0; j < 8; j++) {
        int ee = e + j;
        sidx[j] = esrc[ee < e1 ? ee : e0];
        wt[j] = (ee < e1) ? 1.f : 0.f;
      }
#pragma unroll
      for (int j = 0; j < 8; j++) hv[j] = hsc[(size_t)sidx[j] * 64 + c];
#pragma unroll
      for (int j = 0; j < 8; j++) acc += wt[j] * hv[j];
    }
    at[nn * 65 + c] = dd * acc;
  }
  __syncthreads();
  int tx = tid & 31, ty = tid >> 5;
  int f0 = tx * 4, nn = ty * 4;
  float acc[4][4] = {};
  for (int k = 0; k < 64; k++) {
    float4 wvv = *(float4*)&w1s[k * 128 + f0];
#pragma unroll
    for (int i = 0; i < 4; i++) {
      float av = at[(nn + i) * 65 + k];
      acc[i][0] += av * wvv.x; acc[i][1] += av * wvv.y;
      acc[i][2] += av * wvv.z; acc[i][3] += av * wvv.w;
    }
  }
  float4 bv = *(const float4*)&b1[f0];
#pragma unroll
  for (int i = 0; i < 4; i++) {
    float4 o;
    o.x = selu_f(acc[i][0] + bv.x);
    o.y = selu_f(acc[i][1] + bv.y);
    o.z = selu_f(acc[i][2] + bv.z);
    o.w = selu_f(acc[i][3] + bv.w);
    *(float4*)&xd[(size_t)(n0 + nn + i) * 128 + f0] = o;
  }
}

// ---- s = softmax(xd @ w2 + b2); dual-write ws + out ----
__global__ __launch_bounds__(256) void k_mm2s(const float* xd, const float* w2,
                                              const float* b2, float* s_ws,
                                              float* outs) {  // grid 512
  __shared__ float w2s[128 * 32];
  __shared__ float xt[64 * 129];
  __shared__ float lg[64 * 33];
  int tid = threadIdx.x;
  for (int i = tid; i < 4096; i += 256) w2s[i] = w2[i];
  int n0 = blockIdx.x * 64;
  for (int i = tid; i < 2048; i += 256) {
    int n = i >> 5, j4 = (i & 31) * 4;
    float4 v = *(const float4*)&xd[(size_t)(n0 + n) * 128 + j4];
    xt[n * 129 + j4] = v.x; xt[n * 129 + j4 + 1] = v.y;
    xt[n * 129 + j4 + 2] = v.z; xt[n * 129 + j4 + 3] = v.w;
  }
  __syncthreads();
  int ty = tid >> 3;
  int k0 = (tid & 7) * 4;
  float acc[2][4] = {};
  for (int j = 0; j < 128; j++) {
    float4 wv = *(float4*)&w2s[j * 32 + k0];
    float x0 = xt[(ty * 2) * 129 + j];
    float x1 = xt[(ty * 2 + 1) * 129 + j];
    acc[0][0] += x0 * wv.x; acc[0][1] += x0 * wv.y; acc[0][2] += x0 * wv.z; acc[0][3] += x0 * wv.w;
    acc[1][0] += x1 * wv.x; acc[1][1] += x1 * wv.y; acc[1][2] += x1 * wv.z; acc[1][3] += x1 * wv.w;
  }
  float4 bv = *(const float4*)&b2[k0];
#pragma unroll
  for (int i = 0; i < 2; i++) {
    int n = ty * 2 + i;
    lg[n * 33 + k0]     = acc[i][0] + bv.x;
    lg[n * 33 + k0 + 1] = acc[i][1] + bv.y;
    lg[n * 33 + k0 + 2] = acc[i][2] + bv.z;
    lg[n * 33 + k0 + 3] = acc[i][3] + bv.w;
  }
  __syncthreads();
  if (tid < 64) {
    float m = -3.4e38f;
    for (int kk = 0; kk < 32; kk++) m = fmaxf(m, lg[tid * 33 + kk]);
    float ssum = 0.f;
    for (int kk = 0; kk < 32; kk++) {
      float e = expf(lg[tid * 33 + kk] - m);
      lg[tid * 33 + kk] = e; ssum += e;
    }
    float inv = 1.f / ssum;
    for (int k4 = 0; k4 < 32; k4 += 4) {
      float4 o;
      o.x = lg[tid * 33 + k4] * inv;     o.y = lg[tid * 33 + k4 + 1] * inv;
      o.z = lg[tid * 33 + k4 + 2] * inv; o.w = lg[tid * 33 + k4 + 3] * inv;
      *(float4*)&s_ws[(size_t)(n0 + tid) * 32 + k4] = o;
      float* op = &outs[(size_t)(n0 + tid) * 32 + k4];
      op[0] = o.x; op[1] = o.y; op[2] = o.z; op[3] = o.w;
    }
  }
}

// ---- fused per-chunk stats: S^T S partial, ca/cs partial, spec partial ----
__global__ __launch_bounds__(256) void k_stats(const float* s_ws, const int* cout_,
    const int* ei, float* ssp, float* cap, float* csp, float* specp) { // grid 256
  __shared__ float st[128 * 33];
  __shared__ float r1[8][32], r2[8][32];
  __shared__ float sm4[4];
  int blk = blockIdx.x;
  int b = blk >> 4, chunk = blk & 15;
  int tid = threadIdx.x;
  int nbase = b * 2048 + chunk * 128;
  for (int i = tid; i < 4096; i += 256) {
    int n = i >> 5, kk = i & 31;
    st[n * 33 + kk] = s_ws[(size_t)(nbase + n) * 32 + kk];
  }
  __syncthreads();
  int k = tid >> 3, l0 = (tid & 7) * 4;
  float a0 = 0, a1 = 0, a2 = 0, a3 = 0;
  for (int n = 0; n < 128; n++) {
    float sk = st[n * 33 + k];
    a0 += sk * st[n * 33 + l0];     a1 += sk * st[n * 33 + l0 + 1];
    a2 += sk * st[n * 33 + l0 + 2]; a3 += sk * st[n * 33 + l0 + 3];
  }
  float4 o = {a0, a1, a2, a3};
  *(float4*)&ssp[(size_t)blk * 1024 + k * 32 + l0] = o;
  int k2 = tid & 31, r = tid >> 5;
  float aca = 0.f, acs = 0.f;
  for (int i = 0; i < 16; i++) {
    int n = i * 8 + r;
    float dg = (float)cout_[nbase + n];
    float v = st[n * 33 + k2];
    acs += v; aca += v * dg;
  }
  r1[r][k2] = aca; r2[r][k2] = acs;
  __syncthreads();
  if (r == 0) {
    float sa = 0.f, sc = 0.f;
#pragma unroll
    for (int i = 0; i < 8; i++) { sa += r1[i][k2]; sc += r2[i][k2]; }
    cap[blk * 32 + k2] = sa;
    csp[blk * 32 + k2] = sc;
  }
  int ebase = b * 32768 + chunk * 2048;
  float acc = 0.f;
  for (int j = 0; j < 8; j++) {
    int e = ebase + j * 256 + tid;
    int s = ei[e], d = ei[E_ + e];
    const float4* ap = (const float4*)&s_ws[(size_t)s * 32];
    const float4* cp = (const float4*)&s_ws[(size_t)d * 32];
#pragma unroll
    for (int q = 0; q < 8; q++) {
      float4 u = ap[q], v = cp[q];
      acc += u.x * v.x + u.y * v.y + u.z * v.z + u.w * v.w;
    }
  }
  int lane = tid & 63, w = tid >> 6;
#pragma unroll
  for (int off = 32; off; off >>= 1) acc += __shfl_down(acc, off);
  __syncthreads();
  if (lane == 0) sm4[w] = acc;
  __syncthreads();
  if (tid == 0) specp[blk] = sm4[0] + sm4[1] + sm4[2] + sm4[3];
}

// ---- partial out[b,k,f] over 128-node chunks ----
__global__ __launch_bounds__(256) void k_outp(const float* s_ws, const float* xd,
                                              float* partial) {  // grid 256
  __shared__ float st[64 * 36];
  __shared__ float xt[64 * 132];
  int b = blockIdx.x & 15, chunk = blockIdx.x >> 4;
  int tid = threadIdx.x;
  int tx = tid & 31, ty = tid >> 5;
  int f0 = tx * 4, k0 = ty * 4;
  float acc[4][4] = {};
  for (int sub = 0; sub < 2; sub++) {
    int base = b * 2048 + chunk * 128 + sub * 64;
    __syncthreads();
    for (int i = tid; i < 2048; i += 256) {
      int n = i >> 5, kk = i & 31;
      st[n * 36 + kk] = s_ws[(size_t)(base + n) * 32 + kk];
    }
    for (int i = tid; i < 8192; i += 256) {
      int n = i >> 7, j = i & 127;
      xt[n * 132 + j] = xd[(size_t)(base + n) * 128 + j];
    }
    __syncthreads();
    for (int n = 0; n < 64; n++) {
      float4 sv = *(float4*)&st[n * 36 + k0];
      float4 xv = *(float4*)&xt[n * 132 + f0];
      acc[0][0] += sv.x * xv.x; acc[0][1] += sv.x * xv.y; acc[0][2] += sv.x * xv.z; acc[0][3] += sv.x * xv.w;
      acc[1][0] += sv.y * xv.x; acc[1][1] += sv.y * xv.y; acc[1][2] += sv.y * xv.z; acc[1][3] += sv.y * xv.w;
      acc[2][0] += sv.z * xv.x; acc[2][1] += sv.z * xv.y; acc[2][2] += sv.z * xv.z; acc[2][3] += sv.z * xv.w;
      acc[3][0] += sv.w * xv.x; acc[3][1] += sv.w * xv.y; acc[3][2] += sv.w * xv.z; acc[3][3] += sv.w * xv.w;
    }
  }
  int pbase = (chunk * 16 + b) * 32;
#pragma unroll
  for (int i = 0; i < 4; i++) {
    float4 o = {acc[i][0], acc[i][1], acc[i][2], acc[i][3]};
    *(float4*)&partial[(size_t)(pbase + k0 + i) * 128 + f0] = o;
  }
}

// ---- reduce 16 partials, selu, log_softmax over F=128 ----
__global__ void k_outf(const float* partial, float* out0) {  // grid 512 x 128
  int row = blockIdx.x;
  int b = row >> 5, k = row & 31;
  int f = threadIdx.x;
  float v = 0.f;
#pragma unroll
  for (int c = 0; c < 16; c++) v += partial[(size_t)(((c * 16 + b) * 32 + k)) * 128 + f];
  v = selu_f(v);
  int lane = threadIdx.x & 63, w = threadIdx.x >> 6;
  __shared__ float s1[2], s2[2];
  float m = v;
#pragma unroll
  for (int off = 32; off; off >>= 1) m = fmaxf(m, __shfl_down(m, off));
  if (lane == 0) s1[w] = m;
  __syncthreads();
  m = fmaxf(s1[0], s1[1]);
  float e = expf(v - m), t = e;
#pragma unroll
  for (int off = 32; off; off >>= 1) t += __shfl_down(t, off);
  if (lane == 0) s2[w] = t;
  __syncthreads();
  float tot = s2[0] + s2[1];
  out0[(size_t)row * 128 + f] = v - m - logf(tot);
}

// ---- per-graph losses from partials ----
__global__ void k_loss(const float* ssp, const float* csp, const float* cap,
                       const float* specp, float* loss) { // grid 16 x 256
  int b = blockIdx.x;
  __shared__ float sm[4];
  int tid = threadIdx.x;
  float v0 = 0, v1 = 0, v2 = 0, v3 = 0;
  for (int c = 0; c < 16; c++) {
    float4 u = *(const float4*)&ssp[(size_t)(b * 16 + c) * 1024 + tid * 4];
    v0 += u.x; v1 += u.y; v2 += u.z; v3 += u.w;
  }
  float ssq = v0 * v0 + v1 * v1 + v2 * v2 + v3 * v3;
  ssq = block_sum_bcast(ssq, sm);
  float inv = 1.f / sqrtf(ssq);
  float dsq = 0.f;
  {
    int i0 = tid * 4;
    float vv[4] = {v0, v1, v2, v3};
#pragma unroll
    for (int j = 0; j < 4; j++) {
      int i = i0 + j;
      float d = vv[j] * inv;
      if ((i >> 5) == (i & 31)) d -= 0.17677669529663687f;
      dsq += d * d;
    }
  }
  dsq = block_sum_bcast(dsq, sm);
  float csq = 0.f, casq = 0.f;
  if (tid < 32) {
    float c1 = 0.f, c2 = 0.f;
    for (int c = 0; c < 16; c++) {
      c1 += csp[(size_t)(b * 16 + c) * 32 + tid];
      c2 += cap[(size_t)(b * 16 + c) * 32 + tid];
    }
    csq = c1 * c1; casq = c2 * c2;
  }
  csq = block_sum_bcast(csq, sm);
  casq = block_sum_bcast(casq, sm);
  float spec_sum = (tid < 16) ? specp[b * 16 + tid] : 0.f;
  spec_sum = block_sum_bcast(spec_sum, sm);
  if (tid == 0) {
    float ortho = sqrtf(dsq);
    float cl = sqrtf(csq) * (1.f / 2048.f) * 5.656854249492381f - 1.f;
    float m = 16384.f;
    float spec = -(spec_sum - casq / (2.f * m)) / (2.f * m);
    atomicAdd(loss, (spec + ortho + cl) * (1.f / 16.f));
  }
}

extern "C" void kernel_launch(void* const* d_in, const int* in_sizes, int n_in,
                              void* d_out, int out_size, void* d_ws, size_t ws_size,
                              hipStream_t stream) {
  (void)in_sizes; (void)n_in; (void)out_size; (void)ws_size;
  const float* x   = (const float*)d_in[0];
  const int*   ei  = (const int*)d_in[1];
  const float* gw  = (const float*)d_in[3];
  const float* gb  = (const float*)d_in[4];
  const float* gms = (const float*)d_in[5];
  const float* w1  = (const float*)d_in[6];
  const float* b1  = (const float*)d_in[7];
  const float* w2  = (const float*)d_in[8];
  const float* b2  = (const float*)d_in[9];
  float* out = (float*)d_out;
  float* ws  = (float*)d_ws;

  float* hsc    = ws + OFF_HSC;
  float* xd     = ws + OFF_XD;
  float* s_ws   = ws + OFF_SWS;
  float* part   = ws + OFF_PART;
  float* dinv   = ws + OFF_DINV;
  float* shift  = ws + OFF_SHIFT;
  float* scalev = ws + OFF_SCALE;
  float* gsp    = ws + OFF_GSP;
  float* gsp2   = ws + OFF_GSP2;
  float* ssp    = ws + OFF_SSP;
  float* cap    = ws + OFF_CAP;
  float* csp    = ws + OFF_CSP;
  float* specp  = ws + OFF_SPECP;
  int*   cout_  = (int*)(ws + OFF_ICNTO);
  int*   rows   = (int*)(ws + OFF_IROWS);
  int*   esrc   = (int*)(ws + OFF_IESRC);

  float* out0  = out;            // [B,K,HID]
  float* lossp = out + 65536;    // scalar
  float* outs  = out + 65537;    // [B,N,K]

  hipLaunchKernelGGL(k_graph, dim3(144), dim3(1024), 0, stream,
                     ei, x, rows, esrc, cout_, dinv, gsp, gsp2);
  hipLaunchKernelGGL(k_fin, dim3(1), dim3(1024), 0, stream,
                     gsp, gsp2, gw, gms, shift, scalev, lossp);
  hipLaunchKernelGGL(k_prep, dim3(2048), dim3(256), 0, stream,
                     x, shift, scalev, gb, dinv, hsc);
  hipLaunchKernelGGL(k_mm1, dim3(1024), dim3(256), 0, stream, hsc, dinv, rows, esrc, w1, b1, xd);
  hipLaunchKernelGGL(k_mm2s, dim3(512), dim3(256), 0, stream, xd, w2, b2, s_ws, outs);
  hipLaunchKernelGGL(k_stats, dim3(256), dim3(256), 0, stream, s_ws, cout_, ei, ssp, cap, csp, specp);
  hipLaunchKernelGGL(k_outp, dim3(256), dim3(256), 0, stream, s_ws, xd, part);
  hipLaunchKernelGGL(k_outf, dim3(512), dim3(128), 0, stream, part, out0);
  hipLaunchKernelGGL(k_loss, dim3(16), dim3(256), 0, stream, ssp, csp, cap, specp, lossp);
}

// Round 5
// 214.875 us; speedup vs baseline: 2.3955x; 1.0725x over previous
//
#include <hip/hip_runtime.h>
#include <cmath>

static constexpr int B_  = 16;
static constexpr int N_  = 2048;
static constexpr int NT_ = 32768;
static constexpr int E_  = 524288;

// Workspace layout (float-element offsets)
static constexpr size_t OFF_HSC    = 0;          // NT_*64  (dinv-scaled graphnorm rows)
static constexpr size_t OFF_XD     = 2097152;    // NT_*128
static constexpr size_t OFF_SWS    = 6291456;    // NT_*32
static constexpr size_t OFF_PART   = 7340032;    // 16*16*32*128
static constexpr size_t OFF_DINV   = 8388608;    // NT_
static constexpr size_t OFF_SHIFT  = 8421376;    // 1024
static constexpr size_t OFF_SCALE  = 8422400;    // 1024
static constexpr size_t OFF_GSP    = 8423424;    // 128*64
static constexpr size_t OFF_GSP2   = 8431616;    // 128*64
static constexpr size_t OFF_SSP    = 8439808;    // 256*1024
static constexpr size_t OFF_CAP    = 8701952;    // 256*32
static constexpr size_t OFF_CSP    = 8710144;    // 256*32
static constexpr size_t OFF_SPECP  = 8718336;    // 256
static constexpr size_t OFF_ICNTO  = 8718592;    // 32768 ints (out-degrees)
static constexpr size_t OFF_IROWS  = 8751360;    // 32772
static constexpr size_t OFF_IESRC  = 8784132;    // 524288
// total 9308420 floats = 35.5 MiB

__device__ __forceinline__ float selu_f(float x) {
  return 1.0507009873554805f * (x > 0.f ? x : 1.6732632423543772f * expm1f(x));
}

__device__ __forceinline__ float block_sum_bcast(float v, float* sm) {
  int lane = threadIdx.x & 63, w = threadIdx.x >> 6;
#pragma unroll
  for (int off = 32; off; off >>= 1) v += __shfl_down(v, off);
  __syncthreads();
  if (lane == 0) sm[w] = v;
  __syncthreads();
  return sm[0] + sm[1] + sm[2] + sm[3];
}

// ---- fused: per-graph CSR build (count+scan+bucket, all LDS) + GraphNorm partials ----
__global__ __launch_bounds__(1024) void k_graph(const int* ei, const float* x,
                                                int* rows, int* esrc, int* cout_,
                                                float* dinv, float* gsp, float* gsp2) {
  __shared__ int hin[2048], hout[2048], sb[1024];   // 20 KB
  __shared__ float l1[16][64], l2[16][64];          // 8 KB
  int blk = blockIdx.x;
  int tid = threadIdx.x;
  if (blk < 16) {
    int g = blk;
    int nbase = g * 2048;
    int ebase = g * 32768;
    hin[tid] = 0; hin[tid + 1024] = 0;
    hout[tid] = 0; hout[tid + 1024] = 0;
    __syncthreads();
    for (int i = tid; i < 32768; i += 1024) {
      int s = ei[ebase + i];
      int d = ei[E_ + ebase + i];
      atomicAdd(&hout[s - nbase], 1);
      atomicAdd(&hin[d - nbase], 1);
    }
    __syncthreads();
    int a = hin[2 * tid], b2 = hin[2 * tid + 1];
    sb[tid] = a + b2;
    __syncthreads();
    for (int off = 1; off < 1024; off <<= 1) {
      int add = (tid >= off) ? sb[tid - off] : 0;
      __syncthreads();
      sb[tid] += add;
      __syncthreads();
    }
    int pref = (tid > 0) ? sb[tid - 1] : 0;
    int r0 = ebase + pref, r1 = r0 + a;
    int n0 = nbase + 2 * tid;
    rows[n0] = r0; rows[n0 + 1] = r1;
    dinv[n0] = rsqrtf((float)(a + 1));
    dinv[n0 + 1] = rsqrtf((float)(b2 + 1));
    cout_[n0] = hout[2 * tid];
    cout_[n0 + 1] = hout[2 * tid + 1];
    if (blk == 15 && tid == 1023) rows[NT_] = E_;
    __syncthreads();
    hin[2 * tid] = r0; hin[2 * tid + 1] = r1;
    __syncthreads();
    for (int i = tid; i < 32768; i += 1024) {
      int s = ei[ebase + i];
      int d = ei[E_ + ebase + i];
      int pos = atomicAdd(&hin[d - nbase], 1);
      esrc[pos] = s;
    }
  } else {
    int gi = blk - 16;                // 0..127
    int b = gi >> 3, chunk = gi & 7;
    int c = tid & 63, r = tid >> 6;   // r: 0..15
    float s = 0.f, s2 = 0.f;
    const float* xb = x + ((size_t)b * N_ + (size_t)chunk * 256) * 64;
    for (int n = r; n < 256; n += 16) {
      float v = xb[n * 64 + c];
      s += v; s2 += v * v;
    }
    l1[r][c] = s; l2[r][c] = s2;
    __syncthreads();
    if (r == 0) {
      float t1 = 0.f, t2 = 0.f;
#pragma unroll
      for (int i = 0; i < 16; i++) { t1 += l1[i][c]; t2 += l2[i][c]; }
      gsp[gi * 64 + c] = t1;
      gsp2[gi * 64 + c] = t2;
    }
  }
}

// ---- gn finalize (+ zero loss) ----
__global__ __launch_bounds__(1024) void k_fin(const float* gsp, const float* gsp2,
                                              const float* gw, const float* gms,
                                              float* shift, float* scalev, float* lossp) {
  int t = threadIdx.x;   // grid 1 x 1024
  int b = t >> 6, c = t & 63;
  float s = 0.f, s2 = 0.f;
#pragma unroll
  for (int chunk = 0; chunk < 8; chunk++) {
    s  += gsp[(b * 8 + chunk) * 64 + c];
    s2 += gsp2[(b * 8 + chunk) * 64 + c];
  }
  float mean = s * (1.f / 2048.f);
  float a = gms[c];
  float var = s2 * (1.f / 2048.f) - (2.f * a - a * a) * mean * mean;
  shift[t] = a * mean;
  scalev[t] = gw[c] * rsqrtf(var + 1e-5f);
  if (t == 0) lossp[0] = 0.f;
}

// ---- hsc = dinv * graphnorm(x) ----
__global__ void k_prep(const float* x, const float* shift, const float* scalev,
                       const float* gb, const float* dinv, float* hsc) { // grid 2048 x 256
  int idx = blockIdx.x * 256 + threadIdx.x;
  int node = idx >> 4, g4 = (idx & 15) * 4;
  int b = node >> 11;
  float di = dinv[node];
  float4 xv = *(const float4*)&x[(size_t)node * 64 + g4];
  float4 sh = *(const float4*)&shift[b * 64 + g4];
  float4 sc = *(const float4*)&scalev[b * 64 + g4];
  float4 bb = *(const float4*)&gb[g4];
  float4 o;
  o.x = ((xv.x - sh.x) * sc.x + bb.x) * di;
  o.y = ((xv.y - sh.y) * sc.y + bb.y) * di;
  o.z = ((xv.z - sh.z) * sc.z + bb.z) * di;
  o.w = ((xv.w - sh.w) * sc.w + bb.w) * di;
  *(float4*)&hsc[(size_t)node * 64 + g4] = o;
}

// ---- fused CSR gather (8-deep MLP) + xd = selu(agg @ w1 + b1) ----
// LDS = at-tile only (8.5 KB): w1 is read from global (L2-hot) so occupancy
// is VGPR-bound (~7 blocks/CU) instead of LDS-bound (3 blocks/CU at 41 KB).
__global__ __launch_bounds__(256) void k_mm1(const float* hsc, const float* dinv,
                                             const int* rows, const int* esrc,
                                             const float* w1, const float* b1,
                                             float* xd) {  // grid 1024
  __shared__ float at[32 * 65];
  int tid = threadIdx.x;
  int n0 = blockIdx.x * 32;
  int wv = tid >> 6, c = tid & 63;
  for (int i = 0; i < 8; i++) {
    int nn = i * 4 + wv;
    int node = n0 + nn;
    int e0 = rows[node], e1 = rows[node + 1];
    float dd = dinv[node];
    float acc = hsc[(size_t)node * 64 + c];
    for (int e = e0; e < e1; e += 8) {
      int sidx[8]; float wt[8], hv[8];
#pragma unroll
      for (int j = 0; j < 8; j++) {
        int ee = e + j;
        sidx[j] = esrc[ee < e1 ? ee : e0];
        wt[j] = (ee < e1) ? 1.f : 0.f;
      }
#pragma unroll
      for (int j = 0; j < 8; j++) hv[j] = hsc[(size_t)sidx[j] * 64 + c];
#pragma unroll
      for (int j = 0; j < 8; j++) acc += wt[j] * hv[j];
    }
    at[nn * 65 + c] = dd * acc;
  }
  __syncthreads();
  int tx = tid & 31, ty = tid >> 5;
  int f0 = tx * 4, nn = ty * 4;
  float acc[4][4] = {};
  for (int k = 0; k < 64; k++) {
    float4 wvv = *(const float4*)&w1[k * 128 + f0];
#pragma unroll
    for (int i = 0; i < 4; i++) {
      float av = at[(nn + i) * 65 + k];
      acc[i][0] += av * wvv.x; acc[i][1] += av * wvv.y;
      acc[i][2] += av * wvv.z; acc[i][3] += av * wvv.w;
    }
  }
  float4 bv = *(const float4*)&b1[f0];
#pragma unroll
  for (int i = 0; i < 4; i++) {
    float4 o;
    o.x = selu_f(acc[i][0] + bv.x);
    o.y = selu_f(acc[i][1] + bv.y);
    o.z = selu_f(acc[i][2] + bv.z);
    o.w = selu_f(acc[i][3] + bv.w);
    *(float4*)&xd[(size_t)(n0 + nn + i) * 128 + f0] = o;
  }
}

// ---- s = softmax(xd @ w2 + b2); dual-write ws + out ----
__global__ __launch_bounds__(256) void k_mm2s(const float* xd, const float* w2,
                                              const float* b2, float* s_ws,
                                              float* outs) {  // grid 512
  __shared__ float w2s[128 * 32];
  __shared__ float xt[64 * 129];
  __shared__ float lg[64 * 33];
  int tid = threadIdx.x;
  for (int i = tid; i < 4096; i += 256) w2s[i] = w2[i];
  int n0 = blockIdx.x * 64;
  for (int i = tid; i < 2048; i += 256) {
    int n = i >> 5, j4 = (i & 31) * 4;
    float4 v = *(const float4*)&xd[(size_t)(n0 + n) * 128 + j4];
    xt[n * 129 + j4] = v.x; xt[n * 129 + j4 + 1] = v.y;
    xt[n * 129 + j4 + 2] = v.z; xt[n * 129 + j4 + 3] = v.w;
  }
  __syncthreads();
  int ty = tid >> 3;
  int k0 = (tid & 7) * 4;
  float acc[2][4] = {};
  for (int j = 0; j < 128; j++) {
    float4 wv = *(float4*)&w2s[j * 32 + k0];
    float x0 = xt[(ty * 2) * 129 + j];
    float x1 = xt[(ty * 2 + 1) * 129 + j];
    acc[0][0] += x0 * wv.x; acc[0][1] += x0 * wv.y; acc[0][2] += x0 * wv.z; acc[0][3] += x0 * wv.w;
    acc[1][0] += x1 * wv.x; acc[1][1] += x1 * wv.y; acc[1][2] += x1 * wv.z; acc[1][3] += x1 * wv.w;
  }
  float4 bv = *(const float4*)&b2[k0];
#pragma unroll
  for (int i = 0; i < 2; i++) {
    int n = ty * 2 + i;
    lg[n * 33 + k0]     = acc[i][0] + bv.x;
    lg[n * 33 + k0 + 1] = acc[i][1] + bv.y;
    lg[n * 33 + k0 + 2] = acc[i][2] + bv.z;
    lg[n * 33 + k0 + 3] = acc[i][3] + bv.w;
  }
  __syncthreads();
  if (tid < 64) {
    float m = -3.4e38f;
    for (int kk = 0; kk < 32; kk++) m = fmaxf(m, lg[tid * 33 + kk]);
    float ssum = 0.f;
    for (int kk = 0; kk < 32; kk++) {
      float e = expf(lg[tid * 33 + kk] - m);
      lg[tid * 33 + kk] = e; ssum += e;
    }
    float inv = 1.f / ssum;
    for (int k4 = 0; k4 < 32; k4 += 4) {
      float4 o;
      o.x = lg[tid * 33 + k4] * inv;     o.y = lg[tid * 33 + k4 + 1] * inv;
      o.z = lg[tid * 33 + k4 + 2] * inv; o.w = lg[tid * 33 + k4 + 3] * inv;
      *(float4*)&s_ws[(size_t)(n0 + tid) * 32 + k4] = o;
      float* op = &outs[(size_t)(n0 + tid) * 32 + k4];
      op[0] = o.x; op[1] = o.y; op[2] = o.z; op[3] = o.w;
    }
  }
}

// ---- fused per-chunk stats: S^T S partial, ca/cs partial, spec partial ----
__global__ __launch_bounds__(256) void k_stats(const float* s_ws, const int* cout_,
    const int* ei, float* ssp, float* cap, float* csp, float* specp) { // grid 256
  __shared__ float st[128 * 33];
  __shared__ float r1[8][32], r2[8][32];
  __shared__ float sm4[4];
  int blk = blockIdx.x;
  int b = blk >> 4, chunk = blk & 15;
  int tid = threadIdx.x;
  int nbase = b * 2048 + chunk * 128;
  for (int i = tid; i < 4096; i += 256) {
    int n = i >> 5, kk = i & 31;
    st[n * 33 + kk] = s_ws[(size_t)(nbase + n) * 32 + kk];
  }
  __syncthreads();
  int k = tid >> 3, l0 = (tid & 7) * 4;
  float a0 = 0, a1 = 0, a2 = 0, a3 = 0;
  for (int n = 0; n < 128; n++) {
    float sk = st[n * 33 + k];
    a0 += sk * st[n * 33 + l0];     a1 += sk * st[n * 33 + l0 + 1];
    a2 += sk * st[n * 33 + l0 + 2]; a3 += sk * st[n * 33 + l0 + 3];
  }
  float4 o = {a0, a1, a2, a3};
  *(float4*)&ssp[(size_t)blk * 1024 + k * 32 + l0] = o;
  int k2 = tid & 31, r = tid >> 5;
  float aca = 0.f, acs = 0.f;
  for (int i = 0; i < 16; i++) {
    int n = i * 8 + r;
    float dg = (float)cout_[nbase + n];
    float v = st[n * 33 + k2];
    acs += v; aca += v * dg;
  }
  r1[r][k2] = aca; r2[r][k2] = acs;
  __syncthreads();
  if (r == 0) {
    float sa = 0.f, sc = 0.f;
#pragma unroll
    for (int i = 0; i < 8; i++) { sa += r1[i][k2]; sc += r2[i][k2]; }
    cap[blk * 32 + k2] = sa;
    csp[blk * 32 + k2] = sc;
  }
  int ebase = b * 32768 + chunk * 2048;
  float acc = 0.f;
  for (int j = 0; j < 8; j++) {
    int e = ebase + j * 256 + tid;
    int s = ei[e], d = ei[E_ + e];
    const float4* ap = (const float4*)&s_ws[(size_t)s * 32];
    const float4* cp = (const float4*)&s_ws[(size_t)d * 32];
#pragma unroll
    for (int q = 0; q < 8; q++) {
      float4 u = ap[q], v = cp[q];
      acc += u.x * v.x + u.y * v.y + u.z * v.z + u.w * v.w;
    }
  }
  int lane = tid & 63, w = tid >> 6;
#pragma unroll
  for (int off = 32; off; off >>= 1) acc += __shfl_down(acc, off);
  __syncthreads();
  if (lane == 0) sm4[w] = acc;
  __syncthreads();
  if (tid == 0) specp[blk] = sm4[0] + sm4[1] + sm4[2] + sm4[3];
}

// ---- partial out[b,k,f] over 128-node chunks ----
__global__ __launch_bounds__(256) void k_outp(const float* s_ws, const float* xd,
                                              float* partial) {  // grid 256
  __shared__ float st[64 * 36];
  __shared__ float xt[64 * 132];
  int b = blockIdx.x & 15, chunk = blockIdx.x >> 4;
  int tid = threadIdx.x;
  int tx = tid & 31, ty = tid >> 5;
  int f0 = tx * 4, k0 = ty * 4;
  float acc[4][4] = {};
  for (int sub = 0; sub < 2; sub++) {
    int base = b * 2048 + chunk * 128 + sub * 64;
    __syncthreads();
    for (int i = tid; i < 2048; i += 256) {
      int n = i >> 5, kk = i & 31;
      st[n * 36 + kk] = s_ws[(size_t)(base + n) * 32 + kk];
    }
    for (int i = tid; i < 8192; i += 256) {
      int n = i >> 7, j = i & 127;
      xt[n * 132 + j] = xd[(size_t)(base + n) * 128 + j];
    }
    __syncthreads();
    for (int n = 0; n < 64; n++) {
      float4 sv = *(float4*)&st[n * 36 + k0];
      float4 xv = *(float4*)&xt[n * 132 + f0];
      acc[0][0] += sv.x * xv.x; acc[0][1] += sv.x * xv.y; acc[0][2] += sv.x * xv.z; acc[0][3] += sv.x * xv.w;
      acc[1][0] += sv.y * xv.x; acc[1][1] += sv.y * xv.y; acc[1][2] += sv.y * xv.z; acc[1][3] += sv.y * xv.w;
      acc[2][0] += sv.z * xv.x; acc[2][1] += sv.z * xv.y; acc[2][2] += sv.z * xv.z; acc[2][3] += sv.z * xv.w;
      acc[3][0] += sv.w * xv.x; acc[3][1] += sv.w * xv.y; acc[3][2] += sv.w * xv.z; acc[3][3] += sv.w * xv.w;
    }
  }
  int pbase = (chunk * 16 + b) * 32;
#pragma unroll
  for (int i = 0; i < 4; i++) {
    float4 o = {acc[i][0], acc[i][1], acc[i][2], acc[i][3]};
    *(float4*)&partial[(size_t)(pbase + k0 + i) * 128 + f0] = o;
  }
}

// ---- reduce 16 partials, selu, log_softmax over F=128 ----
__global__ void k_outf(const float* partial, float* out0) {  // grid 512 x 128
  int row = blockIdx.x;
  int b = row >> 5, k = row & 31;
  int f = threadIdx.x;
  float v = 0.f;
#pragma unroll
  for (int c = 0; c < 16; c++) v += partial[(size_t)(((c * 16 + b) * 32 + k)) * 128 + f];
  v = selu_f(v);
  int lane = threadIdx.x & 63, w = threadIdx.x >> 6;
  __shared__ float s1[2], s2[2];
  float m = v;
#pragma unroll
  for (int off = 32; off; off >>= 1) m = fmaxf(m, __shfl_down(m, off));
  if (lane == 0) s1[w] = m;
  __syncthreads();
  m = fmaxf(s1[0], s1[1]);
  float e = expf(v - m), t = e;
#pragma unroll
  for (int off = 32; off; off >>= 1) t += __shfl_down(t, off);
  if (lane == 0) s2[w] = t;
  __syncthreads();
  float tot = s2[0] + s2[1];
  out0[(size_t)row * 128 + f] = v - m - logf(tot);
}

// ---- per-graph losses from partials ----
__global__ void k_loss(const float* ssp, const float* csp, const float* cap,
                       const float* specp, float* loss) { // grid 16 x 256
  int b = blockIdx.x;
  __shared__ float sm[4];
  int tid = threadIdx.x;
  float v0 = 0, v1 = 0, v2 = 0, v3 = 0;
  for (int c = 0; c < 16; c++) {
    float4 u = *(const float4*)&ssp[(size_t)(b * 16 + c) * 1024 + tid * 4];
    v0 += u.x; v1 += u.y; v2 += u.z; v3 += u.w;
  }
  float ssq = v0 * v0 + v1 * v1 + v2 * v2 + v3 * v3;
  ssq = block_sum_bcast(ssq, sm);
  float inv = 1.f / sqrtf(ssq);
  float dsq = 0.f;
  {
    int i0 = tid * 4;
    float vv[4] = {v0, v1, v2, v3};
#pragma unroll
    for (int j = 0; j < 4; j++) {
      int i = i0 + j;
      float d = vv[j] * inv;
      if ((i >> 5) == (i & 31)) d -= 0.17677669529663687f;
      dsq += d * d;
    }
  }
  dsq = block_sum_bcast(dsq, sm);
  float csq = 0.f, casq = 0.f;
  if (tid < 32) {
    float c1 = 0.f, c2 = 0.f;
    for (int c = 0; c < 16; c++) {
      c1 += csp[(size_t)(b * 16 + c) * 32 + tid];
      c2 += cap[(size_t)(b * 16 + c) * 32 + tid];
    }
    csq = c1 * c1; casq = c2 * c2;
  }
  csq = block_sum_bcast(csq, sm);
  casq = block_sum_bcast(casq, sm);
  float spec_sum = (tid < 16) ? specp[b * 16 + tid] : 0.f;
  spec_sum = block_sum_bcast(spec_sum, sm);
  if (tid == 0) {
    float ortho = sqrtf(dsq);
    float cl = sqrtf(csq) * (1.f / 2048.f) * 5.656854249492381f - 1.f;
    float m = 16384.f;
    float spec = -(spec_sum - casq / (2.f * m)) / (2.f * m);
    atomicAdd(loss, (spec + ortho + cl) * (1.f / 16.f));
  }
}

extern "C" void kernel_launch(void* const* d_in, const int* in_sizes, int n_in,
                              void* d_out, int out_size, void* d_ws, size_t ws_size,
                              hipStream_t stream) {
  (void)in_sizes; (void)n_in; (void)out_size; (void)ws_size;
  const float* x   = (const float*)d_in[0];
  const int*   ei  = (const int*)d_in[1];
  const float* gw  = (const float*)d_in[3];
  const float* gb  = (const float*)d_in[4];
  const float* gms = (const float*)d_in[5];
  const float* w1  = (const float*)d_in[6];
  const float* b1  = (const float*)d_in[7];
  const float* w2  = (const float*)d_in[8];
  const float* b2  = (const float*)d_in[9];
  float* out = (float*)d_out;
  float* ws  = (float*)d_ws;

  float* hsc    = ws + OFF_HSC;
  float* xd     = ws + OFF_XD;
  float* s_ws   = ws + OFF_SWS;
  float* part   = ws + OFF_PART;
  float* dinv   = ws + OFF_DINV;
  float* shift  = ws + OFF_SHIFT;
  float* scalev = ws + OFF_SCALE;
  float* gsp    = ws + OFF_GSP;
  float* gsp2   = ws + OFF_GSP2;
  float* ssp    = ws + OFF_SSP;
  float* cap    = ws + OFF_CAP;
  float* csp    = ws + OFF_CSP;
  float* specp  = ws + OFF_SPECP;
  int*   cout_  = (int*)(ws + OFF_ICNTO);
  int*   rows   = (int*)(ws + OFF_IROWS);
  int*   esrc   = (int*)(ws + OFF_IESRC);

  float* out0  = out;            // [B,K,HID]
  float* lossp = out + 65536;    // scalar
  float* outs  = out + 65537;    // [B,N,K]

  hipLaunchKernelGGL(k_graph, dim3(144), dim3(1024), 0, stream,
                     ei, x, rows, esrc, cout_, dinv, gsp, gsp2);
  hipLaunchKernelGGL(k_fin, dim3(1), dim3(1024), 0, stream,
                     gsp, gsp2, gw, gms, shift, scalev, lossp);
  hipLaunchKernelGGL(k_prep, dim3(2048), dim3(256), 0, stream,
                     x, shift, scalev, gb, dinv, hsc);
  hipLaunchKernelGGL(k_mm1, dim3(1024), dim3(256), 0, stream, hsc, dinv, rows, esrc, w1, b1, xd);
  hipLaunchKernelGGL(k_mm2s, dim3(512), dim3(256), 0, stream, xd, w2, b2, s_ws, outs);
  hipLaunchKernelGGL(k_stats, dim3(256), dim3(256), 0, stream, s_ws, cout_, ei, ssp, cap, csp, specp);
  hipLaunchKernelGGL(k_outp, dim3(256), dim3(256), 0, stream, s_ws, xd, part);
  hipLaunchKernelGGL(k_outf, dim3(512), dim3(128), 0, stream, part, out0);
  hipLaunchKernelGGL(k_loss, dim3(16), dim3(256), 0, stream, ssp, csp, cap, specp, lossp);
}

// Round 6
// 207.905 us; speedup vs baseline: 2.4758x; 1.0335x over previous
//
#include <hip/hip_runtime.h>
#include <cmath>

static constexpr int B_  = 16;
static constexpr int N_  = 2048;
static constexpr int NT_ = 32768;
static constexpr int E_  = 524288;

// Workspace layout (float-element offsets)
static constexpr size_t OFF_HSC    = 0;          // NT_*64
static constexpr size_t OFF_XD     = 2097152;    // NT_*128
static constexpr size_t OFF_SWS    = 6291456;    // NT_*32
static constexpr size_t OFF_PART   = 7340032;    // 512*32*128 s^T xd partials
static constexpr size_t OFF_DINV   = 9437184;    // NT_
static constexpr size_t OFF_GSP    = 9469952;    // 128*64
static constexpr size_t OFF_GSP2   = 9478144;    // 128*64
static constexpr size_t OFF_SSP    = 9486336;    // 512*1024
static constexpr size_t OFF_CAP    = 10010624;   // 512*32
static constexpr size_t OFF_CSP    = 10027008;   // 512*32
static constexpr size_t OFF_SPECP  = 10043392;   // 512
static constexpr size_t OFF_ICNTO  = 10043904;   // 32768 ints
static constexpr size_t OFF_IROWS  = 10076672;   // 32772
static constexpr size_t OFF_IESRC  = 10109444;   // 524288
// total 10633732 floats = 40.6 MiB

__device__ __forceinline__ float selu_f(float x) {
  return 1.0507009873554805f * (x > 0.f ? x : 1.6732632423543772f * expm1f(x));
}

__device__ __forceinline__ float block_sum_bcast(float v, float* sm) {
  int lane = threadIdx.x & 63, w = threadIdx.x >> 6;
#pragma unroll
  for (int off = 32; off; off >>= 1) v += __shfl_down(v, off);
  __syncthreads();
  if (lane == 0) sm[w] = v;
  __syncthreads();
  return sm[0] + sm[1] + sm[2] + sm[3];
}

// ---- fused: per-graph CSR build (count+scan+bucket, all LDS) + GraphNorm partials ----
__global__ __launch_bounds__(1024) void k_graph(const int* ei, const float* x,
                                                int* rows, int* esrc, int* cout_,
                                                float* dinv, float* gsp, float* gsp2) {
  __shared__ int hin[2048], hout[2048], sb[1024];   // 20 KB
  __shared__ float l1[16][64], l2[16][64];          // 8 KB
  int blk = blockIdx.x;
  int tid = threadIdx.x;
  if (blk < 16) {
    int g = blk;
    int nbase = g * 2048;
    int ebase = g * 32768;
    hin[tid] = 0; hin[tid + 1024] = 0;
    hout[tid] = 0; hout[tid + 1024] = 0;
    __syncthreads();
    for (int i = tid; i < 32768; i += 1024) {
      int s = ei[ebase + i];
      int d = ei[E_ + ebase + i];
      atomicAdd(&hout[s - nbase], 1);
      atomicAdd(&hin[d - nbase], 1);
    }
    __syncthreads();
    int a = hin[2 * tid], b2 = hin[2 * tid + 1];
    sb[tid] = a + b2;
    __syncthreads();
    for (int off = 1; off < 1024; off <<= 1) {
      int add = (tid >= off) ? sb[tid - off] : 0;
      __syncthreads();
      sb[tid] += add;
      __syncthreads();
    }
    int pref = (tid > 0) ? sb[tid - 1] : 0;
    int r0 = ebase + pref, r1 = r0 + a;
    int n0 = nbase + 2 * tid;
    rows[n0] = r0; rows[n0 + 1] = r1;
    dinv[n0] = rsqrtf((float)(a + 1));
    dinv[n0 + 1] = rsqrtf((float)(b2 + 1));
    cout_[n0] = hout[2 * tid];
    cout_[n0 + 1] = hout[2 * tid + 1];
    if (blk == 15 && tid == 1023) rows[NT_] = E_;
    __syncthreads();
    hin[2 * tid] = r0; hin[2 * tid + 1] = r1;
    __syncthreads();
    for (int i = tid; i < 32768; i += 1024) {
      int s = ei[ebase + i];
      int d = ei[E_ + ebase + i];
      int pos = atomicAdd(&hin[d - nbase], 1);
      esrc[pos] = s;
    }
  } else {
    int gi = blk - 16;                // 0..127
    int b = gi >> 3, chunk = gi & 7;
    int c = tid & 63, r = tid >> 6;   // r: 0..15
    float s = 0.f, s2 = 0.f;
    const float* xb = x + ((size_t)b * N_ + (size_t)chunk * 256) * 64;
    for (int n = r; n < 256; n += 16) {
      float v = xb[n * 64 + c];
      s += v; s2 += v * v;
    }
    l1[r][c] = s; l2[r][c] = s2;
    __syncthreads();
    if (r == 0) {
      float t1 = 0.f, t2 = 0.f;
#pragma unroll
      for (int i = 0; i < 16; i++) { t1 += l1[i][c]; t2 += l2[i][c]; }
      gsp[gi * 64 + c] = t1;
      gsp2[gi * 64 + c] = t2;
    }
  }
}

// ---- hsc = dinv * graphnorm(x)  (gn finalize inlined per-block) ----
__global__ void k_prep(const float* x, const float* gsp, const float* gsp2,
                       const float* gw, const float* gb, const float* gms,
                       const float* dinv, float* hsc) { // grid 2048 x 256
  __shared__ float shs[64], scs[64];
  int tid = threadIdx.x;
  int bgr = blockIdx.x >> 7;          // 16 nodes/block -> 128 blocks/graph
  if (tid < 64) {
    float s = 0.f, s2 = 0.f;
#pragma unroll
    for (int c8 = 0; c8 < 8; c8++) {
      s  += gsp[(bgr * 8 + c8) * 64 + tid];
      s2 += gsp2[(bgr * 8 + c8) * 64 + tid];
    }
    float mean = s * (1.f / 2048.f);
    float a = gms[tid];
    float var = s2 * (1.f / 2048.f) - (2.f * a - a * a) * mean * mean;
    shs[tid] = a * mean;
    scs[tid] = gw[tid] * rsqrtf(var + 1e-5f);
  }
  __syncthreads();
  int idx = blockIdx.x * 256 + tid;
  int node = idx >> 4, g4 = (idx & 15) * 4;
  float di = dinv[node];
  float4 xv = *(const float4*)&x[(size_t)node * 64 + g4];
  float4 bb = *(const float4*)&gb[g4];
  float4 o;
  o.x = ((xv.x - shs[g4])     * scs[g4]     + bb.x) * di;
  o.y = ((xv.y - shs[g4 + 1]) * scs[g4 + 1] + bb.y) * di;
  o.z = ((xv.z - shs[g4 + 2]) * scs[g4 + 2] + bb.z) * di;
  o.w = ((xv.w - shs[g4 + 3]) * scs[g4 + 3] + bb.w) * di;
  *(float4*)&hsc[(size_t)node * 64 + g4] = o;
}

// ---- fused CSR gather (8-deep MLP) + xd = selu(agg @ w1 + b1) ----
__global__ __launch_bounds__(256) void k_mm1(const float* hsc, const float* dinv,
                                             const int* rows, const int* esrc,
                                             const float* w1, const float* b1,
                                             float* xd) {  // grid 1024
  __shared__ float at[32 * 65];
  int tid = threadIdx.x;
  int n0 = blockIdx.x * 32;
  int wv = tid >> 6, c = tid & 63;
  for (int i = 0; i < 8; i++) {
    int nn = i * 4 + wv;
    int node = n0 + nn;
    int e0 = rows[node], e1 = rows[node + 1];
    float dd = dinv[node];
    float acc = hsc[(size_t)node * 64 + c];
    for (int e = e0; e < e1; e += 8) {
      int sidx[8]; float wt[8], hv[8];
#pragma unroll
      for (int j = 0; j < 8; j++) {
        int ee = e + j;
        sidx[j] = esrc[ee < e1 ? ee : e0];
        wt[j] = (ee < e1) ? 1.f : 0.f;
      }
#pragma unroll
      for (int j = 0; j < 8; j++) hv[j] = hsc[(size_t)sidx[j] * 64 + c];
#pragma unroll
      for (int j = 0; j < 8; j++) acc += wt[j] * hv[j];
    }
    at[nn * 65 + c] = dd * acc;
  }
  __syncthreads();
  int tx = tid & 31, ty = tid >> 5;
  int f0 = tx * 4, nn = ty * 4;
  float acc[4][4] = {};
  for (int k = 0; k < 64; k++) {
    float4 wvv = *(const float4*)&w1[k * 128 + f0];
#pragma unroll
    for (int i = 0; i < 4; i++) {
      float av = at[(nn + i) * 65 + k];
      acc[i][0] += av * wvv.x; acc[i][1] += av * wvv.y;
      acc[i][2] += av * wvv.z; acc[i][3] += av * wvv.w;
    }
  }
  float4 bv = *(const float4*)&b1[f0];
#pragma unroll
  for (int i = 0; i < 4; i++) {
    float4 o;
    o.x = selu_f(acc[i][0] + bv.x);
    o.y = selu_f(acc[i][1] + bv.y);
    o.z = selu_f(acc[i][2] + bv.z);
    o.w = selu_f(acc[i][3] + bv.w);
    *(float4*)&xd[(size_t)(n0 + nn + i) * 128 + f0] = o;
  }
}

// ---- mega-fused: s = softmax(xd@w2+b2); then SS/ca/cs partials + s^T xd partial,
//      all from the LDS tiles already resident. grid 512 (64-node chunks).
__global__ __launch_bounds__(256) void k_mm2f(const float* xd, const float* w2,
                                              const float* b2, const int* cout_,
                                              float* s_ws, float* outs, float* ssp,
                                              float* cap, float* csp, float* part) {
  __shared__ float xt[64 * 129];    // 33 KB
  __shared__ float w2s[128 * 32];   // 16 KB
  __shared__ float st[64 * 33];     // 8.4 KB
  __shared__ float r1[8][32], r2[8][32];
  int tid = threadIdx.x;
  int blk = blockIdx.x;
  int n0 = blk * 64;
  for (int i = tid; i < 4096; i += 256) w2s[i] = w2[i];
  for (int i = tid; i < 2048; i += 256) {
    int n = i >> 5, j4 = (i & 31) * 4;
    float4 v = *(const float4*)&xd[(size_t)(n0 + n) * 128 + j4];
    xt[n * 129 + j4] = v.x; xt[n * 129 + j4 + 1] = v.y;
    xt[n * 129 + j4 + 2] = v.z; xt[n * 129 + j4 + 3] = v.w;
  }
  __syncthreads();
  // logits: 2 nodes x 4 clusters per thread
  int ty = tid >> 3;
  int k0 = (tid & 7) * 4;
  float acc2[2][4] = {};
  for (int j = 0; j < 128; j++) {
    float4 wv = *(float4*)&w2s[j * 32 + k0];
    float x0 = xt[(ty * 2) * 129 + j];
    float x1 = xt[(ty * 2 + 1) * 129 + j];
    acc2[0][0] += x0 * wv.x; acc2[0][1] += x0 * wv.y; acc2[0][2] += x0 * wv.z; acc2[0][3] += x0 * wv.w;
    acc2[1][0] += x1 * wv.x; acc2[1][1] += x1 * wv.y; acc2[1][2] += x1 * wv.z; acc2[1][3] += x1 * wv.w;
  }
  float4 bv2 = *(const float4*)&b2[k0];
#pragma unroll
  for (int i = 0; i < 2; i++) {
    int n = ty * 2 + i;
    st[n * 33 + k0]     = acc2[i][0] + bv2.x;
    st[n * 33 + k0 + 1] = acc2[i][1] + bv2.y;
    st[n * 33 + k0 + 2] = acc2[i][2] + bv2.z;
    st[n * 33 + k0 + 3] = acc2[i][3] + bv2.w;
  }
  __syncthreads();
  if (tid < 64) {
    float m = -3.4e38f;
    for (int kk = 0; kk < 32; kk++) m = fmaxf(m, st[tid * 33 + kk]);
    float ssum = 0.f;
    for (int kk = 0; kk < 32; kk++) {
      float e = expf(st[tid * 33 + kk] - m);
      st[tid * 33 + kk] = e; ssum += e;
    }
    float inv = 1.f / ssum;
    for (int kk = 0; kk < 32; kk++) st[tid * 33 + kk] *= inv;
  }
  __syncthreads();
  // write s (both copies) : 512 float4 worth, 2 per thread
  for (int i = tid; i < 512; i += 256) {
    int n = i >> 3, q = (i & 7) * 4;
    float4 o = {st[n * 33 + q], st[n * 33 + q + 1], st[n * 33 + q + 2], st[n * 33 + q + 3]};
    *(float4*)&s_ws[(size_t)(n0 + n) * 32 + q] = o;
    float* op = &outs[(size_t)(n0 + n) * 32 + q];
    op[0] = o.x; op[1] = o.y; op[2] = o.z; op[3] = o.w;
  }
  // SS partial: k = tid>>3, l0 = (tid&7)*4
  {
    int k = tid >> 3, l0 = (tid & 7) * 4;
    float a0 = 0, a1 = 0, a2 = 0, a3 = 0;
    for (int n = 0; n < 64; n++) {
      float sk = st[n * 33 + k];
      a0 += sk * st[n * 33 + l0];     a1 += sk * st[n * 33 + l0 + 1];
      a2 += sk * st[n * 33 + l0 + 2]; a3 += sk * st[n * 33 + l0 + 3];
    }
    float4 o = {a0, a1, a2, a3};
    *(float4*)&ssp[(size_t)blk * 1024 + k * 32 + l0] = o;
  }
  // ca / cs partial
  {
    int k2 = tid & 31, r = tid >> 5;
    float aca = 0.f, acs = 0.f;
    for (int i = 0; i < 8; i++) {
      int n = i * 8 + r;
      float dg = (float)cout_[n0 + n];
      float v = st[n * 33 + k2];
      acs += v; aca += v * dg;
    }
    r1[r][k2] = aca; r2[r][k2] = acs;
    __syncthreads();
    if (r == 0) {
      float sa = 0.f, sc = 0.f;
#pragma unroll
      for (int i = 0; i < 8; i++) { sa += r1[i][k2]; sc += r2[i][k2]; }
      cap[blk * 32 + k2] = sa;
      csp[blk * 32 + k2] = sc;
    }
  }
  // s^T xd partial: 32x128 per chunk
  {
    int tx = tid & 31, ty2 = tid >> 5;
    int f0 = tx * 4, kk0 = ty2 * 4;
    float acc[4][4] = {};
    for (int n = 0; n < 64; n++) {
      float s0 = st[n * 33 + kk0], s1 = st[n * 33 + kk0 + 1];
      float s2 = st[n * 33 + kk0 + 2], s3 = st[n * 33 + kk0 + 3];
      float4 xv = {xt[n * 129 + f0], xt[n * 129 + f0 + 1], xt[n * 129 + f0 + 2], xt[n * 129 + f0 + 3]};
      acc[0][0] += s0 * xv.x; acc[0][1] += s0 * xv.y; acc[0][2] += s0 * xv.z; acc[0][3] += s0 * xv.w;
      acc[1][0] += s1 * xv.x; acc[1][1] += s1 * xv.y; acc[1][2] += s1 * xv.z; acc[1][3] += s1 * xv.w;
      acc[2][0] += s2 * xv.x; acc[2][1] += s2 * xv.y; acc[2][2] += s2 * xv.z; acc[2][3] += s2 * xv.w;
      acc[3][0] += s3 * xv.x; acc[3][1] += s3 * xv.y; acc[3][2] += s3 * xv.z; acc[3][3] += s3 * xv.w;
    }
#pragma unroll
    for (int i = 0; i < 4; i++) {
      float4 o = {acc[i][0], acc[i][1], acc[i][2], acc[i][3]};
      *(float4*)&part[(size_t)(blk * 32 + kk0 + i) * 128 + f0] = o;
    }
  }
}

// ---- spec partials: per-edge dot of s rows (needs complete s); also zero loss ----
__global__ __launch_bounds__(256) void k_spec(const int* ei, const float* s_ws,
                                              float* specp, float* lossp) { // grid 512
  __shared__ float sm4[4];
  int blk = blockIdx.x, tid = threadIdx.x;
  if (blk == 0 && tid == 0) lossp[0] = 0.f;
  int ebase = blk * 1024;
  float acc = 0.f;
#pragma unroll
  for (int j = 0; j < 4; j++) {
    int e = ebase + j * 256 + tid;
    int s = ei[e], d = ei[E_ + e];
    const float4* ap = (const float4*)&s_ws[(size_t)s * 32];
    const float4* cp = (const float4*)&s_ws[(size_t)d * 32];
#pragma unroll
    for (int q = 0; q < 8; q++) {
      float4 u = ap[q], v = cp[q];
      acc += u.x * v.x + u.y * v.y + u.z * v.z + u.w * v.w;
    }
  }
  int lane = tid & 63, w = tid >> 6;
#pragma unroll
  for (int off = 32; off; off >>= 1) acc += __shfl_down(acc, off);
  if (lane == 0) sm4[w] = acc;
  __syncthreads();
  if (tid == 0) specp[blk] = sm4[0] + sm4[1] + sm4[2] + sm4[3];
}

// ---- reduce 32 partials, selu, log_softmax over F=128 ----
__global__ void k_outf(const float* part, float* out0) {  // grid 512 x 128
  int row = blockIdx.x;
  int b = row >> 5, k = row & 31;
  int f = threadIdx.x;
  float v = 0.f;
#pragma unroll
  for (int c = 0; c < 32; c++) v += part[(size_t)((b * 32 + c) * 32 + k) * 128 + f];
  v = selu_f(v);
  int lane = threadIdx.x & 63, w = threadIdx.x >> 6;
  __shared__ float s1[2], s2[2];
  float m = v;
#pragma unroll
  for (int off = 32; off; off >>= 1) m = fmaxf(m, __shfl_down(m, off));
  if (lane == 0) s1[w] = m;
  __syncthreads();
  m = fmaxf(s1[0], s1[1]);
  float e = expf(v - m), t = e;
#pragma unroll
  for (int off = 32; off; off >>= 1) t += __shfl_down(t, off);
  if (lane == 0) s2[w] = t;
  __syncthreads();
  float tot = s2[0] + s2[1];
  out0[(size_t)row * 128 + f] = v - m - logf(tot);
}

// ---- per-graph losses from partials ----
__global__ void k_loss(const float* ssp, const float* csp, const float* cap,
                       const float* specp, float* loss) { // grid 16 x 256
  int b = blockIdx.x;
  __shared__ float sm[4];
  int tid = threadIdx.x;
  float v0 = 0, v1 = 0, v2 = 0, v3 = 0;
  for (int c = 0; c < 32; c++) {
    float4 u = *(const float4*)&ssp[(size_t)(b * 32 + c) * 1024 + tid * 4];
    v0 += u.x; v1 += u.y; v2 += u.z; v3 += u.w;
  }
  float ssq = v0 * v0 + v1 * v1 + v2 * v2 + v3 * v3;
  ssq = block_sum_bcast(ssq, sm);
  float inv = 1.f / sqrtf(ssq);
  float dsq = 0.f;
  {
    int i0 = tid * 4;
    float vv[4] = {v0, v1, v2, v3};
#pragma unroll
    for (int j = 0; j < 4; j++) {
      int i = i0 + j;
      float d = vv[j] * inv;
      if ((i >> 5) == (i & 31)) d -= 0.17677669529663687f;  // 1/sqrt(32)
      dsq += d * d;
    }
  }
  dsq = block_sum_bcast(dsq, sm);
  float csq = 0.f, casq = 0.f;
  if (tid < 32) {
    float c1 = 0.f, c2 = 0.f;
    for (int c = 0; c < 32; c++) {
      c1 += csp[(size_t)(b * 32 + c) * 32 + tid];
      c2 += cap[(size_t)(b * 32 + c) * 32 + tid];
    }
    csq = c1 * c1; casq = c2 * c2;
  }
  csq = block_sum_bcast(csq, sm);
  casq = block_sum_bcast(casq, sm);
  float spec_sum = (tid < 32) ? specp[b * 32 + tid] : 0.f;
  spec_sum = block_sum_bcast(spec_sum, sm);
  if (tid == 0) {
    float ortho = sqrtf(dsq);
    float cl = sqrtf(csq) * (1.f / 2048.f) * 5.656854249492381f - 1.f;
    float m = 16384.f;
    float spec = -(spec_sum - casq / (2.f * m)) / (2.f * m);
    atomicAdd(loss, (spec + ortho + cl) * (1.f / 16.f));
  }
}

extern "C" void kernel_launch(void* const* d_in, const int* in_sizes, int n_in,
                              void* d_out, int out_size, void* d_ws, size_t ws_size,
                              hipStream_t stream) {
  (void)in_sizes; (void)n_in; (void)out_size; (void)ws_size;
  const float* x   = (const float*)d_in[0];
  const int*   ei  = (const int*)d_in[1];
  const float* gw  = (const float*)d_in[3];
  const float* gb  = (const float*)d_in[4];
  const float* gms = (const float*)d_in[5];
  const float* w1  = (const float*)d_in[6];
  const float* b1  = (const float*)d_in[7];
  const float* w2  = (const float*)d_in[8];
  const float* b2  = (const float*)d_in[9];
  float* out = (float*)d_out;
  float* ws  = (float*)d_ws;

  float* hsc    = ws + OFF_HSC;
  float* xd     = ws + OFF_XD;
  float* s_ws   = ws + OFF_SWS;
  float* part   = ws + OFF_PART;
  float* dinv   = ws + OFF_DINV;
  float* gsp    = ws + OFF_GSP;
  float* gsp2   = ws + OFF_GSP2;
  float* ssp    = ws + OFF_SSP;
  float* cap    = ws + OFF_CAP;
  float* csp    = ws + OFF_CSP;
  float* specp  = ws + OFF_SPECP;
  int*   cout_  = (int*)(ws + OFF_ICNTO);
  int*   rows   = (int*)(ws + OFF_IROWS);
  int*   esrc   = (int*)(ws + OFF_IESRC);

  float* out0  = out;            // [B,K,HID]
  float* lossp = out + 65536;    // scalar
  float* outs  = out + 65537;    // [B,N,K]

  hipLaunchKernelGGL(k_graph, dim3(144), dim3(1024), 0, stream,
                     ei, x, rows, esrc, cout_, dinv, gsp, gsp2);
  hipLaunchKernelGGL(k_prep, dim3(2048), dim3(256), 0, stream,
                     x, gsp, gsp2, gw, gb, gms, dinv, hsc);
  hipLaunchKernelGGL(k_mm1, dim3(1024), dim3(256), 0, stream, hsc, dinv, rows, esrc, w1, b1, xd);
  hipLaunchKernelGGL(k_mm2f, dim3(512), dim3(256), 0, stream,
                     xd, w2, b2, cout_, s_ws, outs, ssp, cap, csp, part);
  hipLaunchKernelGGL(k_spec, dim3(512), dim3(256), 0, stream, ei, s_ws, specp, lossp);
  hipLaunchKernelGGL(k_outf, dim3(512), dim3(128), 0, stream, part, out0);
  hipLaunchKernelGGL(k_loss, dim3(16), dim3(256), 0, stream, ssp, csp, cap, specp, lossp);
}